// Round 4
// baseline (211.407 us; speedup 1.0000x reference)
//
#include <hip/hip_runtime.h>
#include <hip/hip_bf16.h>
#include <math.h>
#include <stdint.h>

// Problem constants
#define S_LEN  2048
#define HID    1024
#define NHEADS 16
#define NE     256
#define NMEN   1024
#define NP     2048
#define PHID   1024

typedef __attribute__((ext_vector_type(8))) short bf16x8;
typedef __attribute__((ext_vector_type(4))) float f32x4;
typedef unsigned int uint;

// ---------------------------------------------------------------------------
// Helpers
// ---------------------------------------------------------------------------
__device__ inline void seg_bounds(const int* __restrict__ entity_ids, int e,
                                  int& start, int& end) {
    int lo = 0, hi = NMEN;
    while (lo < hi) { int mid = (lo + hi) >> 1; if (entity_ids[mid] < e) lo = mid + 1; else hi = mid; }
    start = lo;
    hi = NMEN;
    while (lo < hi) { int mid = (lo + hi) >> 1; if (entity_ids[mid] <= e) lo = mid + 1; else hi = mid; }
    end = lo;
}

__device__ __forceinline__ void load_lds16(const void* g, void* l) {
    __builtin_amdgcn_global_load_lds(
        (const __attribute__((address_space(1))) uint32_t*)g,
        (__attribute__((address_space(3))) uint32_t*)l,
        16, 0, 0);
}

__device__ __forceinline__ float bflo(uint u) { return __uint_as_float(u << 16); }
__device__ __forceinline__ float bfhi(uint u) { return __uint_as_float(u & 0xffff0000u); }
__device__ __forceinline__ uint pk2(float a, float b) {
    __hip_bfloat16 ha = __float2bfloat16(a), hb = __float2bfloat16(b);
    unsigned short ua = *(unsigned short*)&ha, ub = *(unsigned short*)&hb;
    return (uint)ua | ((uint)ub << 16);
}

// ---------------------------------------------------------------------------
// 0) seq fp32 -> bf16 cast (no transpose) + out = b_bil init (blocks 0..7)
//    grid 1024 x 256; each thread converts 8 consecutive floats
// ---------------------------------------------------------------------------
__global__ void cast_bias_kernel(const float4* __restrict__ in4, uint4* __restrict__ o8,
                                 const float* __restrict__ b_bil, float* __restrict__ logits)
{
    long i = (long)blockIdx.x * 256 + threadIdx.x;   // S*H/8 = 262144 total
    float4 a = in4[2 * i], b = in4[2 * i + 1];
    uint4 o;
    o.x = pk2(a.x, a.y); o.y = pk2(a.z, a.w);
    o.z = pk2(b.x, b.y); o.w = pk2(b.z, b.w);
    o8[i] = o;
    if (blockIdx.x < 8) logits[blockIdx.x * 256 + threadIdx.x] = b_bil[0];
}

// 4 weight matrices [1024][1024] transpose->bf16 in one launch
__global__ void transpose4_bf16(const float* __restrict__ w0, const float* __restrict__ w1,
                                const float* __restrict__ w2, const float* __restrict__ w3,
                                __hip_bfloat16* __restrict__ o0, __hip_bfloat16* __restrict__ o1,
                                __hip_bfloat16* __restrict__ o2, __hip_bfloat16* __restrict__ o3)
{
    __shared__ float t[32][33];
    const float* in = (blockIdx.z == 0) ? w0 : (blockIdx.z == 1) ? w1 : (blockIdx.z == 2) ? w2 : w3;
    __hip_bfloat16* out = (blockIdx.z == 0) ? o0 : (blockIdx.z == 1) ? o1 : (blockIdx.z == 2) ? o2 : o3;
    int r0 = blockIdx.y * 32, c0 = blockIdx.x * 32;
    int j = threadIdx.x & 31, i0 = threadIdx.x >> 5;
    for (int i = i0; i < 32; i += 8)
        t[i][j] = in[(long)(r0 + i) * 1024 + c0 + j];
    __syncthreads();
    for (int i = i0; i < 32; i += 8)
        out[(long)(c0 + i) * 1024 + r0 + j] = __float2bfloat16(t[j][i]);
}

// ---------------------------------------------------------------------------
// 1) Entity embedding: segment logsumexp -> bf16 [E][H]
// ---------------------------------------------------------------------------
__global__ void ent_emb_kernel(const float4* __restrict__ seq4,
                               const int* __restrict__ mention_idx,
                               const int* __restrict__ entity_ids,
                               __hip_bfloat16* __restrict__ ent_emb)
{
    __shared__ int sb[2];
    int e = blockIdx.x;
    if (threadIdx.x == 0) { int s, t; seg_bounds(entity_ids, e, s, t); sb[0] = s; sb[1] = t; }
    __syncthreads();
    int start = sb[0], end = sb[1];
    int col4 = threadIdx.x;
    uint2 o;
    if (end <= start) {
        o.x = 0; o.y = 0;
        ((uint2*)ent_emb)[(long)e * 256 + col4] = o;
        return;
    }
    float mx = -INFINITY, my = -INFINITY, mz = -INFINITY, mw = -INFINITY;
    for (int i = start; i < end; ++i) {
        float4 v = seq4[(long)mention_idx[i] * 256 + col4];
        mx = fmaxf(mx, v.x); my = fmaxf(my, v.y); mz = fmaxf(mz, v.z); mw = fmaxf(mw, v.w);
    }
    float sx = 0.f, sy = 0.f, sz = 0.f, sw = 0.f;
    for (int i = start; i < end; ++i) {
        float4 v = seq4[(long)mention_idx[i] * 256 + col4];
        sx += expf(v.x - mx); sy += expf(v.y - my); sz += expf(v.z - mz); sw += expf(v.w - mw);
    }
    o.x = pk2(mx + logf(sx), my + logf(sy));
    o.y = pk2(mz + logf(sz), mw + logf(sw));
    ((uint2*)ent_emb)[(long)e * 256 + col4] = o;
}

// ---------------------------------------------------------------------------
// 2) Entity attention: segment mean -> bf16 [E][HEADS][S]
// ---------------------------------------------------------------------------
__global__ void ent_att_kernel(const float4* __restrict__ att4,
                               const int* __restrict__ mention_idx,
                               const int* __restrict__ entity_ids,
                               uint2* __restrict__ out)
{
    __shared__ int sb[2];
    int e = blockIdx.x, h = blockIdx.y;
    if (threadIdx.x == 0) { int s, t; seg_bounds(entity_ids, e, s, t); sb[0] = s; sb[1] = t; }
    __syncthreads();
    int start = sb[0], end = sb[1];
    float inv = 1.f / fmaxf((float)(end - start), 1.f);
    for (int s4 = threadIdx.x; s4 < S_LEN / 4; s4 += 256) {
        float ax = 0.f, ay = 0.f, az = 0.f, aw = 0.f;
        for (int i = start; i < end; ++i) {
            float4 v = att4[((long)h * S_LEN + mention_idx[i]) * (S_LEN / 4) + s4];
            ax += v.x; ay += v.y; az += v.z; aw += v.w;
        }
        uint2 o; o.x = pk2(ax * inv, ay * inv); o.y = pk2(az * inv, aw * inv);
        out[((long)e * NHEADS + h) * (S_LEN / 4) + s4] = o;
    }
}

// ---------------------------------------------------------------------------
// 3) Pair attention: bf16 in, bf16 normalized out
// ---------------------------------------------------------------------------
__global__ void pair_att_kernel(const uint4* __restrict__ ea,
                                const int* __restrict__ pair_h,
                                const int* __restrict__ pair_t,
                                uint4* __restrict__ patt)
{
    __shared__ float wsum[4];
    int p = blockIdx.x;
    long bh = (long)pair_h[p] * NHEADS * (S_LEN / 8);
    long bt = (long)pair_t[p] * NHEADS * (S_LEN / 8);
    int s8 = threadIdx.x;
    float a0 = 0, a1 = 0, a2 = 0, a3 = 0, a4 = 0, a5 = 0, a6 = 0, a7 = 0;
#pragma unroll
    for (int h = 0; h < NHEADS; ++h) {
        uint4 xa = ea[bh + h * (S_LEN / 8) + s8];
        uint4 xb = ea[bt + h * (S_LEN / 8) + s8];
        a0 += bflo(xa.x) * bflo(xb.x); a1 += bfhi(xa.x) * bfhi(xb.x);
        a2 += bflo(xa.y) * bflo(xb.y); a3 += bfhi(xa.y) * bfhi(xb.y);
        a4 += bflo(xa.z) * bflo(xb.z); a5 += bfhi(xa.z) * bfhi(xb.z);
        a6 += bflo(xa.w) * bflo(xb.w); a7 += bfhi(xa.w) * bfhi(xb.w);
    }
    float psum = a0 + a1 + a2 + a3 + a4 + a5 + a6 + a7;
#pragma unroll
    for (int off = 32; off > 0; off >>= 1)
        psum += __shfl_down(psum, off, 64);
    int lane = threadIdx.x & 63, wid = threadIdx.x >> 6;
    if (lane == 0) wsum[wid] = psum;
    __syncthreads();
    float inv = 1.f / (wsum[0] + wsum[1] + wsum[2] + wsum[3] + 1e-6f);
    uint4 o;
    o.x = pk2(a0 * inv, a1 * inv); o.y = pk2(a2 * inv, a3 * inv);
    o.z = pk2(a4 * inv, a5 * inv); o.w = pk2(a6 * inv, a7 * inv);
    patt[(long)p * (S_LEN / 8) + s8] = o;
}

// ---------------------------------------------------------------------------
// 4) bf16 MFMA GEMM, 128x128 tile, BK=32, 4 waves (2x2), split-K via blockIdx.z.
//    MODE 0: write fp32 partial slice at Cout + z*M*N
//    MODE 2: fused bilinear: atomicAdd(out+row, sum_col acc*zo[row][col])
// ---------------------------------------------------------------------------
template <int MODE>
__launch_bounds__(256)
__global__ void gemm_bt(const __hip_bfloat16* __restrict__ A,
                        const __hip_bfloat16* __restrict__ Bt,
                        float* __restrict__ Cout,
                        const float* __restrict__ zo,
                        float* __restrict__ out,
                        int M, int N, int Kstride, int kLen)
{
    __shared__ short As[4][128][8];
    __shared__ short Bs[4][128][8];

    int tid = threadIdx.x;
    int lane = tid & 63, wid = tid >> 6;
    int wr = wid >> 1, wc = wid & 1;
    int bm = blockIdx.y * 128, bn = blockIdx.x * 128;
    int kBeg = blockIdx.z * kLen;

    const __hip_bfloat16* gsrc[4];
    void* ldst[4];
#pragma unroll
    for (int i = 0; i < 4; ++i) {
        int c = wid * 4 + i;
        int isA = (c < 8) ? 1 : 0;
        int cc = isA ? c : c - 8;
        int kg = cc >> 1, rh = cc & 1;
        gsrc[i] = (isA ? A + (long)(bm + rh * 64 + lane) * Kstride
                       : Bt + (long)(bn + rh * 64 + lane) * Kstride) + kBeg + kg * 8;
        ldst[i] = isA ? (void*)&As[kg][rh * 64][0] : (void*)&Bs[kg][rh * 64][0];
    }

    f32x4 acc[4][4] = {};
    int kg = lane >> 4, lr = lane & 15;

    for (int k0 = 0; k0 < kLen; k0 += 32) {
#pragma unroll
        for (int i = 0; i < 4; ++i)
            load_lds16(gsrc[i] + k0, ldst[i]);
        __syncthreads();

        bf16x8 af[4], bfr[4];
#pragma unroll
        for (int f = 0; f < 4; ++f) {
            af[f]  = *(const bf16x8*)&As[kg][wr * 64 + f * 16 + lr][0];
            bfr[f] = *(const bf16x8*)&Bs[kg][wc * 64 + f * 16 + lr][0];
        }
#pragma unroll
        for (int fm = 0; fm < 4; ++fm)
#pragma unroll
            for (int fn = 0; fn < 4; ++fn)
                acc[fm][fn] = __builtin_amdgcn_mfma_f32_16x16x32_bf16(af[fm], bfr[fn], acc[fm][fn], 0, 0, 0);
        __syncthreads();
    }

    int q4 = (lane >> 4) * 4;
    if (MODE == 0) {
#pragma unroll
        for (int fm = 0; fm < 4; ++fm)
#pragma unroll
            for (int fn = 0; fn < 4; ++fn) {
                int row = bm + wr * 64 + fm * 16 + q4;
                int col = bn + wc * 64 + fn * 16 + lr;
#pragma unroll
                for (int r = 0; r < 4; ++r)
                    Cout[((long)blockIdx.z * M + row + r) * N + col] = acc[fm][fn][r];
            }
    } else {
#pragma unroll
        for (int fm = 0; fm < 4; ++fm) {
#pragma unroll
            for (int r = 0; r < 4; ++r) {
                int row = bm + wr * 64 + fm * 16 + q4 + r;
                float v = 0.f;
#pragma unroll
                for (int fn = 0; fn < 4; ++fn) {
                    int col = bn + wc * 64 + fn * 16 + lr;
                    v += acc[fm][fn][r] * zo[(long)row * N + col];
                }
                v += __shfl_xor(v, 1, 64);
                v += __shfl_xor(v, 2, 64);
                v += __shfl_xor(v, 4, 64);
                v += __shfl_xor(v, 8, 64);
                if (lr == 0) atomicAdd(out + row, v);
            }
        }
    }
}

// ---------------------------------------------------------------------------
// 5) Fused zs/zo GEMM: C = pattB[2048][2048] @ seqWT[1024][2048]^T, then
//    zs = tanh(ehet[ph][j] + b_head[j] + C), zo = tanh(ehet[pt][1024+j] + b_tail[j] + C)
//    128x64 tile, full K (no split), 4 waves (2x2, each 64x32)
// ---------------------------------------------------------------------------
__launch_bounds__(256)
__global__ void gemm_zs_zo(const __hip_bfloat16* __restrict__ A,
                           const __hip_bfloat16* __restrict__ Bt,
                           const float* __restrict__ ehet,    // [E][2048]
                           const float* __restrict__ b_head,
                           const float* __restrict__ b_tail,
                           const int* __restrict__ pair_h,
                           const int* __restrict__ pair_t,
                           __hip_bfloat16* __restrict__ zs, float* __restrict__ zo)
{
    __shared__ short As[4][128][8];
    __shared__ short Bs[4][64][8];
    const int Kstride = S_LEN;

    int tid = threadIdx.x;
    int lane = tid & 63, wid = tid >> 6;
    int wr = wid >> 1, wc = wid & 1;
    int bm = blockIdx.y * 128, bn = blockIdx.x * 64;

    // 12 chunks of 1KB: 8 A (kg,rh), 4 B (kg). 3 per wave.
    const __hip_bfloat16* gsrc[3];
    void* ldst[3];
#pragma unroll
    for (int i = 0; i < 3; ++i) {
        int c = wid * 3 + i;
        if (c < 8) {
            int kg = c >> 1, rh = c & 1;
            gsrc[i] = A + (long)(bm + rh * 64 + lane) * Kstride + kg * 8;
            ldst[i] = (void*)&As[kg][rh * 64][0];
        } else {
            int kg = c - 8;
            gsrc[i] = Bt + (long)(bn + lane) * Kstride + kg * 8;
            ldst[i] = (void*)&Bs[kg][0][0];
        }
    }

    f32x4 acc[4][2] = {};
    int kg = lane >> 4, lr = lane & 15;

    for (int k0 = 0; k0 < S_LEN; k0 += 32) {
#pragma unroll
        for (int i = 0; i < 3; ++i)
            load_lds16(gsrc[i] + k0, ldst[i]);
        __syncthreads();

        bf16x8 af[4], bfr[2];
#pragma unroll
        for (int f = 0; f < 4; ++f)
            af[f] = *(const bf16x8*)&As[kg][wr * 64 + f * 16 + lr][0];
#pragma unroll
        for (int f = 0; f < 2; ++f)
            bfr[f] = *(const bf16x8*)&Bs[kg][wc * 32 + f * 16 + lr][0];
#pragma unroll
        for (int fm = 0; fm < 4; ++fm)
#pragma unroll
            for (int fn = 0; fn < 2; ++fn)
                acc[fm][fn] = __builtin_amdgcn_mfma_f32_16x16x32_bf16(af[fm], bfr[fn], acc[fm][fn], 0, 0, 0);
        __syncthreads();
    }

    int q4 = (lane >> 4) * 4;
#pragma unroll
    for (int fn = 0; fn < 2; ++fn) {
        int col = bn + wc * 32 + fn * 16 + lr;
        float bh = b_head[col], bt = b_tail[col];
#pragma unroll
        for (int fm = 0; fm < 4; ++fm) {
#pragma unroll
            for (int r = 0; r < 4; ++r) {
                int row = bm + wr * 64 + fm * 16 + q4 + r;
                float c = acc[fm][fn][r];
                int ph = pair_h[row], pt = pair_t[row];
                float hv = tanhf(ehet[(long)ph * 2048 + col] + bh + c);
                float tv = tanhf(ehet[(long)pt * 2048 + 1024 + col] + bt + c);
                zs[(long)row * PHID + col] = __float2bfloat16(hv);
                zo[(long)row * PHID + col] = tv;
            }
        }
    }
}

// ---------------------------------------------------------------------------
// 6) reductions
// ---------------------------------------------------------------------------
__global__ void reduce2_bf16(const float* __restrict__ part, __hip_bfloat16* __restrict__ o, long n)
{
    long i = (long)blockIdx.x * 256 + threadIdx.x;
    o[i] = __float2bfloat16(part[i] + part[n + i]);
}

__global__ void reduce4_f32(const float* __restrict__ part, float* __restrict__ o, long n)
{
    long i = (long)blockIdx.x * 256 + threadIdx.x;
    o[i] = part[i] + part[n + i] + part[2 * n + i] + part[3 * n + i];
}

// ---------------------------------------------------------------------------
// Launch
// ---------------------------------------------------------------------------
extern "C" void kernel_launch(void* const* d_in, const int* in_sizes, int n_in,
                              void* d_out, int out_size, void* d_ws, size_t ws_size,
                              hipStream_t stream)
{
    const float* seq        = (const float*)d_in[0];
    const float* attention  = (const float*)d_in[1];
    const int*   mention_idx= (const int*)  d_in[2];
    const int*   entity_ids = (const int*)  d_in[3];
    const int*   pair_h     = (const int*)  d_in[4];
    const int*   pair_t     = (const int*)  d_in[5];
    const float* W_head     = (const float*)d_in[6];
    const float* b_head     = (const float*)d_in[7];
    const float* W_tail     = (const float*)d_in[8];
    const float* b_tail     = (const float*)d_in[9];
    const float* W_ctx      = (const float*)d_in[10];
    const float* W_bil      = (const float*)d_in[11];
    const float* b_bil      = (const float*)d_in[12];
    float* out = (float*)d_out;

    // ---- workspace (MB offsets) ----
    char* w = (char*)d_ws;
    __hip_bfloat16* seqB  = (__hip_bfloat16*)(w + 0);          // [S][H] bf16    4 MB
    __hip_bfloat16* WctxT = (__hip_bfloat16*)(w + (4l << 20)); // [PH][H]        2 MB
    __hip_bfloat16* WhtT  = (__hip_bfloat16*)(w + (6l << 20)); // [2PH][H]       4 MB
    __hip_bfloat16* WbilT = (__hip_bfloat16*)(w + (10l << 20));// [PH][PH]       2 MB
    __hip_bfloat16* embB  = (__hip_bfloat16*)(w + (12l << 20));// [E][H]         0.5 MB
    __hip_bfloat16* eaB   = (__hip_bfloat16*)(w + (13l << 20));// [E][16][S]     16 MB
    __hip_bfloat16* pattB = (__hip_bfloat16*)(w + (29l << 20));// [P][S]         8 MB
    __hip_bfloat16* seqWT = (__hip_bfloat16*)(w + (37l << 20));// [PH][S]        4 MB
    __hip_bfloat16* zsB   = (__hip_bfloat16*)(w + (41l << 20));// [P][PH]        4 MB
    float* zo    = (float*)(w + (45l << 20));                  // [P][PH]        8 MB
    float* spart = (float*)(w + (53l << 20));                  // [2][PH][S]     16 MB
    float* ehetP = (float*)(w + (69l << 20));                  // [4][E][2PH]    8 MB
    float* ehet  = (float*)(w + (77l << 20));                  // [E][2PH]       2 MB

    // ---- 0) seq cast + out=b_bil; weight transposes ----
    cast_bias_kernel<<<1024, 256, 0, stream>>>((const float4*)seq, (uint4*)seqB, b_bil, out);
    transpose4_bf16<<<dim3(32, 32, 4), 256, 0, stream>>>(W_ctx, W_head, W_tail, W_bil,
                                                         WctxT, WhtT, WhtT + (long)PHID * HID, WbilT);

    // ---- 1) entity embeddings (bf16) ----
    ent_emb_kernel<<<NE, 256, 0, stream>>>((const float4*)seq, mention_idx, entity_ids, embB);

    // ---- 2) entity attention (bf16) ----
    ent_att_kernel<<<dim3(NE, NHEADS), 256, 0, stream>>>((const float4*)attention, mention_idx, entity_ids,
                                                         (uint2*)eaB);

    // ---- 3) pair attention (bf16 normalized) ----
    pair_att_kernel<<<NP, 256, 0, stream>>>((const uint4*)eaB, pair_h, pair_t, (uint4*)pattB);

    // ---- 4) seqWT[j][s] = (seq @ W_ctx)^T : A=WctxT, Bt=seqB, M=1024,N=2048,K=1024, splitK=2 ----
    gemm_bt<0><<<dim3(S_LEN / 128, PHID / 128, 2), 256, 0, stream>>>(WctxT, seqB, spart, nullptr, nullptr,
                                                                     PHID, S_LEN, HID, HID / 2);
    reduce2_bf16<<<(int)(((long)PHID * S_LEN) / 256), 256, 0, stream>>>(spart, seqWT, (long)PHID * S_LEN);

    // ---- 5) ehet partials = ent_emb @ [W_head|W_tail], splitK=4, then fp32 reduce ----
    gemm_bt<0><<<dim3(2 * PHID / 128, NE / 128, 4), 256, 0, stream>>>(embB, WhtT, ehetP, nullptr, nullptr,
                                                                      NE, 2 * PHID, HID, HID / 4);
    reduce4_f32<<<(int)(((long)NE * 2 * PHID) / 256), 256, 0, stream>>>(ehetP, ehet, (long)NE * 2 * PHID);

    // ---- 6) fused: ctxp = pattB @ seqWT^T, epilogue tanh -> zs (bf16), zo (f32) ----
    gemm_zs_zo<<<dim3(PHID / 64, NP / 128), 256, 0, stream>>>(pattB, seqWT, ehet, b_head, b_tail,
                                                              pair_h, pair_t, zsB, zo);

    // ---- 7) fused bilinear: out[p] += sum_j (zs@W_bil)[p,j] * zo[p,j], splitK=2 ----
    gemm_bt<2><<<dim3(PHID / 128, NP / 128, 2), 256, 0, stream>>>(zsB, WbilT, nullptr, zo, out,
                                                                  NP, PHID, HID, HID / 2);
}

// Round 5
// 182.093 us; speedup vs baseline: 1.1610x; 1.1610x over previous
//
#include <hip/hip_runtime.h>
#include <hip/hip_bf16.h>
#include <math.h>
#include <stdint.h>

// Problem constants
#define S_LEN  2048
#define HID    1024
#define NHEADS 16
#define NE     256
#define NMEN   1024
#define NP     2048
#define PHID   1024

typedef __attribute__((ext_vector_type(8))) short bf16x8;
typedef __attribute__((ext_vector_type(4))) float f32x4;
typedef unsigned int uint;

// ---------------------------------------------------------------------------
// Helpers
// ---------------------------------------------------------------------------
__device__ inline void seg_bounds(const int* __restrict__ entity_ids, int e,
                                  int& start, int& end) {
    int lo = 0, hi = NMEN;
    while (lo < hi) { int mid = (lo + hi) >> 1; if (entity_ids[mid] < e) lo = mid + 1; else hi = mid; }
    start = lo;
    hi = NMEN;
    while (lo < hi) { int mid = (lo + hi) >> 1; if (entity_ids[mid] <= e) lo = mid + 1; else hi = mid; }
    end = lo;
}

__device__ __forceinline__ void load_lds16(const void* g, void* l) {
    __builtin_amdgcn_global_load_lds(
        (const __attribute__((address_space(1))) uint32_t*)g,
        (__attribute__((address_space(3))) uint32_t*)l,
        16, 0, 0);
}

__device__ __forceinline__ float bflo(uint u) { return __uint_as_float(u << 16); }
__device__ __forceinline__ float bfhi(uint u) { return __uint_as_float(u & 0xffff0000u); }
__device__ __forceinline__ uint pk2(float a, float b) {
    __hip_bfloat16 ha = __float2bfloat16(a), hb = __float2bfloat16(b);
    unsigned short ua = *(unsigned short*)&ha, ub = *(unsigned short*)&hb;
    return (uint)ua | ((uint)ub << 16);
}

// ---------------------------------------------------------------------------
// 0) Merged prep: z<4 -> weight transposes (y<32), z==4 -> seq transpose
//    grid (32, 64, 5), 256 threads
// ---------------------------------------------------------------------------
__global__ void prep_kernel(const float* __restrict__ seq,
                            const float* __restrict__ w0, const float* __restrict__ w1,
                            const float* __restrict__ w2, const float* __restrict__ w3,
                            __hip_bfloat16* __restrict__ seqT,
                            __hip_bfloat16* __restrict__ o0, __hip_bfloat16* __restrict__ o1,
                            __hip_bfloat16* __restrict__ o2, __hip_bfloat16* __restrict__ o3)
{
    __shared__ float t[32][33];
    const float* in;
    __hip_bfloat16* out;
    int R, C;
    if (blockIdx.z < 4) {
        if (blockIdx.y >= 32) return;
        in = (blockIdx.z == 0) ? w0 : (blockIdx.z == 1) ? w1 : (blockIdx.z == 2) ? w2 : w3;
        out = (blockIdx.z == 0) ? o0 : (blockIdx.z == 1) ? o1 : (blockIdx.z == 2) ? o2 : o3;
        R = 1024; C = 1024;
    } else {
        in = seq; out = seqT; R = S_LEN; C = HID;
    }
    int r0 = blockIdx.y * 32, c0 = blockIdx.x * 32;
    int j = threadIdx.x & 31, i0 = threadIdx.x >> 5;
    for (int i = i0; i < 32; i += 8)
        t[i][j] = in[(long)(r0 + i) * C + c0 + j];
    __syncthreads();
    for (int i = i0; i < 32; i += 8)
        out[(long)(c0 + i) * R + r0 + j] = __float2bfloat16(t[j][i]);
}

// ---------------------------------------------------------------------------
// 1+2) Merged entity kernel: grid (NE, 17). y<16: ent_att head y; y==16: ent_emb
// ---------------------------------------------------------------------------
__global__ void ent_kernel(const float4* __restrict__ att4,      // [HEADS][S][S/4]
                           const float4* __restrict__ seq4,      // [S][H/4]
                           const int* __restrict__ mention_idx,
                           const int* __restrict__ entity_ids,
                           uint2* __restrict__ eaB,               // [E*HEADS][S/4] bf16-packed
                           __hip_bfloat16* __restrict__ ent_emb)  // [E][H]
{
    __shared__ int sb[2];
    int e = blockIdx.x;
    if (threadIdx.x == 0) { int s, t; seg_bounds(entity_ids, e, s, t); sb[0] = s; sb[1] = t; }
    __syncthreads();
    int start = sb[0], end = sb[1];

    if (blockIdx.y < 16) {
        int h = blockIdx.y;
        float inv = 1.f / fmaxf((float)(end - start), 1.f);
        for (int s4 = threadIdx.x; s4 < S_LEN / 4; s4 += 256) {
            float ax = 0.f, ay = 0.f, az = 0.f, aw = 0.f;
            for (int i = start; i < end; ++i) {
                float4 v = att4[((long)h * S_LEN + mention_idx[i]) * (S_LEN / 4) + s4];
                ax += v.x; ay += v.y; az += v.z; aw += v.w;
            }
            uint2 o; o.x = pk2(ax * inv, ay * inv); o.y = pk2(az * inv, aw * inv);
            eaB[((long)e * NHEADS + h) * (S_LEN / 4) + s4] = o;
        }
    } else {
        int col4 = threadIdx.x;
        uint2 o;
        if (end <= start) {
            o.x = 0; o.y = 0;
            ((uint2*)ent_emb)[(long)e * 256 + col4] = o;
            return;
        }
        float mx = -INFINITY, my = -INFINITY, mz = -INFINITY, mw = -INFINITY;
        for (int i = start; i < end; ++i) {
            float4 v = seq4[(long)mention_idx[i] * 256 + col4];
            mx = fmaxf(mx, v.x); my = fmaxf(my, v.y); mz = fmaxf(mz, v.z); mw = fmaxf(mw, v.w);
        }
        float sx = 0.f, sy = 0.f, sz = 0.f, sw = 0.f;
        for (int i = start; i < end; ++i) {
            float4 v = seq4[(long)mention_idx[i] * 256 + col4];
            sx += expf(v.x - mx); sy += expf(v.y - my); sz += expf(v.z - mz); sw += expf(v.w - mw);
        }
        o.x = pk2(mx + logf(sx), my + logf(sy));
        o.y = pk2(mz + logf(sz), mw + logf(sw));
        ((uint2*)ent_emb)[(long)e * 256 + col4] = o;
    }
}

// ---------------------------------------------------------------------------
// 3) Pair attention: bf16 in, bf16 normalized out
// ---------------------------------------------------------------------------
__global__ void pair_att_kernel(const uint4* __restrict__ ea,
                                const int* __restrict__ pair_h,
                                const int* __restrict__ pair_t,
                                uint4* __restrict__ patt)
{
    __shared__ float wsum[4];
    int p = blockIdx.x;
    long bh = (long)pair_h[p] * NHEADS * (S_LEN / 8);
    long bt = (long)pair_t[p] * NHEADS * (S_LEN / 8);
    int s8 = threadIdx.x;
    float a0 = 0, a1 = 0, a2 = 0, a3 = 0, a4 = 0, a5 = 0, a6 = 0, a7 = 0;
#pragma unroll
    for (int h = 0; h < NHEADS; ++h) {
        uint4 xa = ea[bh + h * (S_LEN / 8) + s8];
        uint4 xb = ea[bt + h * (S_LEN / 8) + s8];
        a0 += bflo(xa.x) * bflo(xb.x); a1 += bfhi(xa.x) * bfhi(xb.x);
        a2 += bflo(xa.y) * bflo(xb.y); a3 += bfhi(xa.y) * bfhi(xb.y);
        a4 += bflo(xa.z) * bflo(xb.z); a5 += bfhi(xa.z) * bfhi(xb.z);
        a6 += bflo(xa.w) * bflo(xb.w); a7 += bfhi(xa.w) * bfhi(xb.w);
    }
    float psum = a0 + a1 + a2 + a3 + a4 + a5 + a6 + a7;
#pragma unroll
    for (int off = 32; off > 0; off >>= 1)
        psum += __shfl_down(psum, off, 64);
    int lane = threadIdx.x & 63, wid = threadIdx.x >> 6;
    if (lane == 0) wsum[wid] = psum;
    __syncthreads();
    float inv = 1.f / (wsum[0] + wsum[1] + wsum[2] + wsum[3] + 1e-6f);
    uint4 o;
    o.x = pk2(a0 * inv, a1 * inv); o.y = pk2(a2 * inv, a3 * inv);
    o.z = pk2(a4 * inv, a5 * inv); o.w = pk2(a6 * inv, a7 * inv);
    patt[(long)p * (S_LEN / 8) + s8] = o;
}

// ---------------------------------------------------------------------------
// 4) bf16 MFMA GEMM core: 128x128 tile, BK=64 (32 KB LDS), 4 waves (2x2).
//    MODE 0: Cout[(bz*M + row)*N + col] = acc (fp32 split-K partial)
//    MODE 2: fused bilinear: atomicAdd(out+row, sum_col acc*zo[row][col])
// ---------------------------------------------------------------------------
template <int MODE>
__device__ __forceinline__ void gemm_core(
    const __hip_bfloat16* __restrict__ A,
    const __hip_bfloat16* __restrict__ Bt,
    float* __restrict__ Cout, const float* __restrict__ zo, float* __restrict__ out,
    int M, int N, int Kstride, int kLen,
    int bx, int by, int bz,
    short (*As)[128][8], short (*Bs)[128][8])
{
    int tid = threadIdx.x;
    int lane = tid & 63, wid = tid >> 6;
    int wr = wid >> 1, wc = wid & 1;
    int bm = by * 128, bn = bx * 128;
    int kBeg = bz * kLen;

    // 32 chunks of 1 KB (16 A + 16 B), 8 per wave
    const __hip_bfloat16* gsrc[8];
    void* ldst[8];
#pragma unroll
    for (int i = 0; i < 8; ++i) {
        int c = wid * 8 + i;
        int isA = (c < 16) ? 1 : 0;
        int cc = isA ? c : c - 16;
        int kg2 = cc >> 1, rh = cc & 1;
        gsrc[i] = (isA ? A + (long)(bm + rh * 64 + lane) * Kstride
                       : Bt + (long)(bn + rh * 64 + lane) * Kstride) + kBeg + kg2 * 8;
        ldst[i] = isA ? (void*)&As[kg2][rh * 64][0] : (void*)&Bs[kg2][rh * 64][0];
    }

    f32x4 acc[4][4] = {};
    int kg = lane >> 4, lr = lane & 15;

    for (int k0 = 0; k0 < kLen; k0 += 64) {
#pragma unroll
        for (int i = 0; i < 8; ++i)
            load_lds16(gsrc[i] + k0, ldst[i]);
        __syncthreads();
#pragma unroll
        for (int sub = 0; sub < 2; ++sub) {
            bf16x8 af[4], bfr[4];
#pragma unroll
            for (int f = 0; f < 4; ++f) {
                af[f]  = *(const bf16x8*)&As[sub * 4 + kg][wr * 64 + f * 16 + lr][0];
                bfr[f] = *(const bf16x8*)&Bs[sub * 4 + kg][wc * 64 + f * 16 + lr][0];
            }
#pragma unroll
            for (int fm = 0; fm < 4; ++fm)
#pragma unroll
                for (int fn = 0; fn < 4; ++fn)
                    acc[fm][fn] = __builtin_amdgcn_mfma_f32_16x16x32_bf16(af[fm], bfr[fn], acc[fm][fn], 0, 0, 0);
        }
        __syncthreads();
    }

    int q4 = (lane >> 4) * 4;
    if (MODE == 0) {
#pragma unroll
        for (int fm = 0; fm < 4; ++fm)
#pragma unroll
            for (int fn = 0; fn < 4; ++fn) {
                int row = bm + wr * 64 + fm * 16 + q4;
                int col = bn + wc * 64 + fn * 16 + lr;
#pragma unroll
                for (int r = 0; r < 4; ++r)
                    Cout[((long)bz * M + row + r) * N + col] = acc[fm][fn][r];
            }
    } else {
#pragma unroll
        for (int fm = 0; fm < 4; ++fm) {
#pragma unroll
            for (int r = 0; r < 4; ++r) {
                int row = bm + wr * 64 + fm * 16 + q4 + r;
                float v = 0.f;
#pragma unroll
                for (int fn = 0; fn < 4; ++fn) {
                    int col = bn + wc * 64 + fn * 16 + lr;
                    v += acc[fm][fn][r] * zo[(long)row * N + col];
                }
                v += __shfl_xor(v, 1, 64);
                v += __shfl_xor(v, 2, 64);
                v += __shfl_xor(v, 4, 64);
                v += __shfl_xor(v, 8, 64);
                if (lr == 0) atomicAdd(out + row, v);
            }
        }
    }
}

// Combined launch: contexts (splitK=2) + ehet (splitK=4), grid (16,16,2)
__launch_bounds__(256)
__global__ void gemm_ctx_ehet(const __hip_bfloat16* __restrict__ pattB,
                              const __hip_bfloat16* __restrict__ seqT,
                              float* __restrict__ cpart,
                              const __hip_bfloat16* __restrict__ embB,
                              const __hip_bfloat16* __restrict__ WhtT,
                              float* __restrict__ ehetP)
{
    __shared__ short As[8][128][8];
    __shared__ short Bs[8][128][8];
    if (blockIdx.x < 8) {
        // contexts: M=2048, N=1024, K=2048, splitK=2 (kLen=1024)
        gemm_core<0>(pattB, seqT, cpart, nullptr, nullptr,
                     NP, HID, S_LEN, S_LEN / 2, blockIdx.x, blockIdx.y, blockIdx.z, As, Bs);
    } else {
        if (blockIdx.z != 0) return;
        // ehet: M=256, N=2048, K=1024, splitK=4 (kLen=256): remap 128 spare blocks
        int u = (blockIdx.x - 8) * 16 + blockIdx.y;   // 0..127
        int ex = u & 15, ey = (u >> 4) & 1, ez = u >> 5;
        gemm_core<0>(embB, WhtT, ehetP, nullptr, nullptr,
                     NE, 2 * PHID, HID, HID / 4, ex, ey, ez, As, Bs);
    }
}

template <int MODE>
__launch_bounds__(256)
__global__ void gemm_single(const __hip_bfloat16* __restrict__ A,
                            const __hip_bfloat16* __restrict__ Bt,
                            float* __restrict__ Cout,
                            const float* __restrict__ zo,
                            float* __restrict__ out,
                            int M, int N, int Kstride, int kLen)
{
    __shared__ short As[8][128][8];
    __shared__ short Bs[8][128][8];
    gemm_core<MODE>(A, Bt, Cout, zo, out, M, N, Kstride, kLen,
                    blockIdx.x, blockIdx.y, blockIdx.z, As, Bs);
}

// ---------------------------------------------------------------------------
// 5) merged reduce: blocks [0,8192): ctx 2-slice -> bf16; [8192,10240): ehet 4-slice -> f32
// ---------------------------------------------------------------------------
__global__ void reduce_both(const float* __restrict__ cpart, __hip_bfloat16* __restrict__ ctxB,
                            const float* __restrict__ ehetP, float* __restrict__ ehet)
{
    long b = blockIdx.x;
    if (b < 8192) {
        long i = b * 256 + threadIdx.x;
        const long n = (long)NP * HID;
        ctxB[i] = __float2bfloat16(cpart[i] + cpart[n + i]);
    } else {
        long i = (b - 8192) * 256 + threadIdx.x;
        const long n = (long)NE * 2 * PHID;
        ehet[i] = ehetP[i] + ehetP[n + i] + ehetP[2 * n + i] + ehetP[3 * n + i];
    }
}

// ---------------------------------------------------------------------------
// 6) zs/zo (+ out = b_bil init): folds ctxp 2-slice sum
// ---------------------------------------------------------------------------
__global__ void zs_zo_kernel(const float* __restrict__ ctxpP,  // [2][P][PH]
                             const float* __restrict__ ehet,   // [E][2PH]
                             const float* __restrict__ b_head,
                             const float* __restrict__ b_tail,
                             const int* __restrict__ pair_h,
                             const int* __restrict__ pair_t,
                             __hip_bfloat16* __restrict__ zs, float* __restrict__ zo,
                             const float* __restrict__ b_bil, float* __restrict__ out)
{
    long idx = (long)blockIdx.x * 256 + threadIdx.x;
    if (idx < NP) out[idx] = b_bil[0];
    int p = (int)(idx >> 10);
    int j = (int)(idx & (PHID - 1));
    float c = ctxpP[idx] + ctxpP[(long)NP * PHID + idx];
    float hs = ehet[(long)pair_h[p] * 2048 + j] + b_head[j] + c;
    float ts = ehet[(long)pair_t[p] * 2048 + 1024 + j] + b_tail[j] + c;
    zs[idx] = __float2bfloat16(tanhf(hs));
    zo[idx] = tanhf(ts);
}

// ---------------------------------------------------------------------------
// Launch
// ---------------------------------------------------------------------------
extern "C" void kernel_launch(void* const* d_in, const int* in_sizes, int n_in,
                              void* d_out, int out_size, void* d_ws, size_t ws_size,
                              hipStream_t stream)
{
    const float* seq        = (const float*)d_in[0];
    const float* attention  = (const float*)d_in[1];
    const int*   mention_idx= (const int*)  d_in[2];
    const int*   entity_ids = (const int*)  d_in[3];
    const int*   pair_h     = (const int*)  d_in[4];
    const int*   pair_t     = (const int*)  d_in[5];
    const float* W_head     = (const float*)d_in[6];
    const float* b_head     = (const float*)d_in[7];
    const float* W_tail     = (const float*)d_in[8];
    const float* b_tail     = (const float*)d_in[9];
    const float* W_ctx      = (const float*)d_in[10];
    const float* W_bil      = (const float*)d_in[11];
    const float* b_bil      = (const float*)d_in[12];
    float* out = (float*)d_out;

    // ---- workspace (MB offsets) ----
    char* w = (char*)d_ws;
    __hip_bfloat16* seqT  = (__hip_bfloat16*)(w + 0);          // [H][S]      4 MB
    __hip_bfloat16* WctxT = (__hip_bfloat16*)(w + (4l << 20)); // [PH][H]     2 MB
    __hip_bfloat16* WhtT  = (__hip_bfloat16*)(w + (6l << 20)); // [2PH][H]    4 MB
    __hip_bfloat16* WbilT = (__hip_bfloat16*)(w + (10l << 20));// [PH][PH]    2 MB
    __hip_bfloat16* embB  = (__hip_bfloat16*)(w + (12l << 20));// [E][H]      0.5 MB
    __hip_bfloat16* eaB   = (__hip_bfloat16*)(w + (13l << 20));// [E][16][S]  16 MB
    __hip_bfloat16* pattB = (__hip_bfloat16*)(w + (29l << 20));// [P][S]      8 MB
    __hip_bfloat16* ctxB  = (__hip_bfloat16*)(w + (37l << 20));// [P][H]      4 MB
    __hip_bfloat16* zsB   = (__hip_bfloat16*)(w + (41l << 20));// [P][PH]     4 MB
    float* zo    = (float*)(w + (45l << 20));                  // [P][PH]     8 MB
    float* cpart = (float*)(w + (53l << 20));                  // [2][P][H]   16 MB
    float* ctxpP = (float*)(w + (69l << 20));                  // [2][P][PH]  16 MB
    float* ehetP = (float*)(w + (85l << 20));                  // [4][E][2PH] 8 MB
    float* ehet  = (float*)(w + (93l << 20));                  // [E][2PH]    2 MB

    // ---- 1) prep: seq transpose + 4 weight transposes ----
    prep_kernel<<<dim3(32, 64, 5), 256, 0, stream>>>(seq, W_ctx, W_head, W_tail, W_bil,
                                                     seqT, WctxT, WhtT, WhtT + (long)PHID * HID, WbilT);

    // ---- 2) entity embeddings + entity attention ----
    ent_kernel<<<dim3(NE, 17), 256, 0, stream>>>((const float4*)attention, (const float4*)seq,
                                                 mention_idx, entity_ids, (uint2*)eaB, embB);

    // ---- 3) pair attention ----
    pair_att_kernel<<<NP, 256, 0, stream>>>((const uint4*)eaB, pair_h, pair_t, (uint4*)pattB);

    // ---- 4) contexts (splitK=2) + ehet (splitK=4) in one launch ----
    gemm_ctx_ehet<<<dim3(16, 16, 2), 256, 0, stream>>>(pattB, seqT, cpart, embB, WhtT, ehetP);

    // ---- 5) merged reduce: ctxB (bf16) + ehet (f32) ----
    reduce_both<<<10240, 256, 0, stream>>>(cpart, ctxB, ehetP, ehet);

    // ---- 6) ctxp partials = contexts @ W_ctx, splitK=2 ----
    gemm_single<0><<<dim3(8, 16, 2), 256, 0, stream>>>(ctxB, WctxT, ctxpP, nullptr, nullptr,
                                                       NP, PHID, HID, HID / 2);

    // ---- 7) zs/zo + out=b_bil ----
    zs_zo_kernel<<<8192, 256, 0, stream>>>(ctxpP, ehet, b_head, b_tail, pair_h, pair_t,
                                           zsB, zo, b_bil, out);

    // ---- 8) fused bilinear, splitK=2 ----
    gemm_single<2><<<dim3(8, 16, 2), 256, 0, stream>>>(zsB, WbilT, nullptr, zo, out,
                                                       NP, PHID, HID, HID / 2);
}

// Round 6
// 180.011 us; speedup vs baseline: 1.1744x; 1.0116x over previous
//
#include <hip/hip_runtime.h>
#include <hip/hip_bf16.h>
#include <math.h>
#include <stdint.h>

// Problem constants
#define S_LEN  2048
#define HID    1024
#define NHEADS 16
#define NE     256
#define NMEN   1024
#define NP     2048
#define PHID   1024

typedef __attribute__((ext_vector_type(8))) short bf16x8;
typedef __attribute__((ext_vector_type(4))) float f32x4;
typedef unsigned int uint;

// ---------------------------------------------------------------------------
// Helpers
// ---------------------------------------------------------------------------
__device__ inline void seg_bounds(const int* __restrict__ entity_ids, int e,
                                  int& start, int& end) {
    int lo = 0, hi = NMEN;
    while (lo < hi) { int mid = (lo + hi) >> 1; if (entity_ids[mid] < e) lo = mid + 1; else hi = mid; }
    start = lo;
    hi = NMEN;
    while (lo < hi) { int mid = (lo + hi) >> 1; if (entity_ids[mid] <= e) lo = mid + 1; else hi = mid; }
    end = lo;
}

__device__ __forceinline__ void load_lds16(const void* g, void* l) {
    __builtin_amdgcn_global_load_lds(
        (const __attribute__((address_space(1))) uint32_t*)g,
        (__attribute__((address_space(3))) uint32_t*)l,
        16, 0, 0);
}

__device__ __forceinline__ float bflo(uint u) { return __uint_as_float(u << 16); }
__device__ __forceinline__ float bfhi(uint u) { return __uint_as_float(u & 0xffff0000u); }
__device__ __forceinline__ uint pk2(float a, float b) {
    __hip_bfloat16 ha = __float2bfloat16(a), hb = __float2bfloat16(b);
    unsigned short ua = *(unsigned short*)&ha, ub = *(unsigned short*)&hb;
    return (uint)ua | ((uint)ub << 16);
}

// ---------------------------------------------------------------------------
// 0+1+2) Merged prep + entity kernel, flat 1D grid of 10496 blocks:
//   [0,2048)      seq transpose -> seqT [H][S] bf16
//   [2048,6144)   4 weight transposes
//   [6144,10496)  entity: e = t&255, role = t>>8 (0..15: att head; 16: emb)
// ---------------------------------------------------------------------------
__device__ __forceinline__ void transpose32(const float* __restrict__ in,
                                            __hip_bfloat16* __restrict__ out,
                                            int R, int C, int r0, int c0,
                                            float (*t)[33])
{
    int j = threadIdx.x & 31, i0 = threadIdx.x >> 5;
    for (int i = i0; i < 32; i += 8)
        t[i][j] = in[(long)(r0 + i) * C + c0 + j];
    __syncthreads();
    for (int i = i0; i < 32; i += 8)
        out[(long)(c0 + i) * R + r0 + j] = __float2bfloat16(t[j][i]);
}

__global__ void prep_ent_kernel(const float* __restrict__ seq,
                                const float* __restrict__ attention,
                                const float* __restrict__ w0, const float* __restrict__ w1,
                                const float* __restrict__ w2, const float* __restrict__ w3,
                                const int* __restrict__ mention_idx,
                                const int* __restrict__ entity_ids,
                                __hip_bfloat16* __restrict__ seqT,
                                __hip_bfloat16* __restrict__ o0, __hip_bfloat16* __restrict__ o1,
                                __hip_bfloat16* __restrict__ o2, __hip_bfloat16* __restrict__ o3,
                                uint2* __restrict__ eaB,
                                __hip_bfloat16* __restrict__ ent_emb)
{
    __shared__ float tbuf[32][33];
    int id = blockIdx.x;
    if (id < 2048) {
        // seq [2048][1024] -> seqT [1024][2048]
        int c0 = (id & 31) * 32, r0 = (id >> 5) * 32;
        transpose32(seq, seqT, S_LEN, HID, r0, c0, tbuf);
        return;
    }
    if (id < 6144) {
        int t = id - 2048;
        int z = t >> 10;
        const float* in = (z == 0) ? w0 : (z == 1) ? w1 : (z == 2) ? w2 : w3;
        __hip_bfloat16* out = (z == 0) ? o0 : (z == 1) ? o1 : (z == 2) ? o2 : o3;
        int r0 = ((t >> 5) & 31) * 32, c0 = (t & 31) * 32;
        transpose32(in, out, 1024, 1024, r0, c0, tbuf);
        return;
    }
    // entity work
    int t = id - 6144;
    int e = t & 255, role = t >> 8;
    __shared__ int sb[2];
    if (threadIdx.x == 0) { int s, tt; seg_bounds(entity_ids, e, s, tt); sb[0] = s; sb[1] = tt; }
    __syncthreads();
    int start = sb[0], end = sb[1];

    if (role < 16) {
        const float4* att4 = (const float4*)attention;
        int h = role;
        float inv = 1.f / fmaxf((float)(end - start), 1.f);
        for (int s4 = threadIdx.x; s4 < S_LEN / 4; s4 += 256) {
            float ax = 0.f, ay = 0.f, az = 0.f, aw = 0.f;
            for (int i = start; i < end; ++i) {
                float4 v = att4[((long)h * S_LEN + mention_idx[i]) * (S_LEN / 4) + s4];
                ax += v.x; ay += v.y; az += v.z; aw += v.w;
            }
            uint2 o; o.x = pk2(ax * inv, ay * inv); o.y = pk2(az * inv, aw * inv);
            eaB[((long)e * NHEADS + h) * (S_LEN / 4) + s4] = o;
        }
    } else {
        const float4* seq4 = (const float4*)seq;
        int col4 = threadIdx.x;
        uint2 o;
        if (end <= start) {
            o.x = 0; o.y = 0;
            ((uint2*)ent_emb)[(long)e * 256 + col4] = o;
            return;
        }
        float mx = -INFINITY, my = -INFINITY, mz = -INFINITY, mw = -INFINITY;
        for (int i = start; i < end; ++i) {
            float4 v = seq4[(long)mention_idx[i] * 256 + col4];
            mx = fmaxf(mx, v.x); my = fmaxf(my, v.y); mz = fmaxf(mz, v.z); mw = fmaxf(mw, v.w);
        }
        float sx = 0.f, sy = 0.f, sz = 0.f, sw = 0.f;
        for (int i = start; i < end; ++i) {
            float4 v = seq4[(long)mention_idx[i] * 256 + col4];
            sx += expf(v.x - mx); sy += expf(v.y - my); sz += expf(v.z - mz); sw += expf(v.w - mw);
        }
        o.x = pk2(mx + logf(sx), my + logf(sy));
        o.y = pk2(mz + logf(sz), mw + logf(sw));
        ((uint2*)ent_emb)[(long)e * 256 + col4] = o;
    }
}

// ---------------------------------------------------------------------------
// 3) Pair attention: bf16 in, bf16 normalized out
// ---------------------------------------------------------------------------
__global__ void pair_att_kernel(const uint4* __restrict__ ea,
                                const int* __restrict__ pair_h,
                                const int* __restrict__ pair_t,
                                uint4* __restrict__ patt)
{
    __shared__ float wsum[4];
    int p = blockIdx.x;
    long bh = (long)pair_h[p] * NHEADS * (S_LEN / 8);
    long bt = (long)pair_t[p] * NHEADS * (S_LEN / 8);
    int s8 = threadIdx.x;
    float a0 = 0, a1 = 0, a2 = 0, a3 = 0, a4 = 0, a5 = 0, a6 = 0, a7 = 0;
#pragma unroll
    for (int h = 0; h < NHEADS; ++h) {
        uint4 xa = ea[bh + h * (S_LEN / 8) + s8];
        uint4 xb = ea[bt + h * (S_LEN / 8) + s8];
        a0 += bflo(xa.x) * bflo(xb.x); a1 += bfhi(xa.x) * bfhi(xb.x);
        a2 += bflo(xa.y) * bflo(xb.y); a3 += bfhi(xa.y) * bfhi(xb.y);
        a4 += bflo(xa.z) * bflo(xb.z); a5 += bfhi(xa.z) * bfhi(xb.z);
        a6 += bflo(xa.w) * bflo(xb.w); a7 += bfhi(xa.w) * bfhi(xb.w);
    }
    float psum = a0 + a1 + a2 + a3 + a4 + a5 + a6 + a7;
#pragma unroll
    for (int off = 32; off > 0; off >>= 1)
        psum += __shfl_down(psum, off, 64);
    int lane = threadIdx.x & 63, wid = threadIdx.x >> 6;
    if (lane == 0) wsum[wid] = psum;
    __syncthreads();
    float inv = 1.f / (wsum[0] + wsum[1] + wsum[2] + wsum[3] + 1e-6f);
    uint4 o;
    o.x = pk2(a0 * inv, a1 * inv); o.y = pk2(a2 * inv, a3 * inv);
    o.z = pk2(a4 * inv, a5 * inv); o.w = pk2(a6 * inv, a7 * inv);
    patt[(long)p * (S_LEN / 8) + s8] = o;
}

// ---------------------------------------------------------------------------
// 4) bf16 MFMA GEMM core: 128x128 tile, BK=64 (32 KB LDS), 4 waves (2x2).
//    MODE 0: Cout[(bz*M + row)*N + col] = acc (fp32 split-K partial)
//    MODE 2: fused bilinear: atomicAdd(out+row, sum_col acc*zo[row][col])
// ---------------------------------------------------------------------------
template <int MODE>
__device__ __forceinline__ void gemm_core(
    const __hip_bfloat16* __restrict__ A,
    const __hip_bfloat16* __restrict__ Bt,
    float* __restrict__ Cout, const float* __restrict__ zo, float* __restrict__ out,
    int M, int N, int Kstride, int kLen,
    int bx, int by, int bz,
    short (*As)[128][8], short (*Bs)[128][8])
{
    int tid = threadIdx.x;
    int lane = tid & 63, wid = tid >> 6;
    int wr = wid >> 1, wc = wid & 1;
    int bm = by * 128, bn = bx * 128;
    int kBeg = bz * kLen;

    // 32 chunks of 1 KB (16 A + 16 B), 8 per wave
    const __hip_bfloat16* gsrc[8];
    void* ldst[8];
#pragma unroll
    for (int i = 0; i < 8; ++i) {
        int c = wid * 8 + i;
        int isA = (c < 16) ? 1 : 0;
        int cc = isA ? c : c - 16;
        int kg2 = cc >> 1, rh = cc & 1;
        gsrc[i] = (isA ? A + (long)(bm + rh * 64 + lane) * Kstride
                       : Bt + (long)(bn + rh * 64 + lane) * Kstride) + kBeg + kg2 * 8;
        ldst[i] = isA ? (void*)&As[kg2][rh * 64][0] : (void*)&Bs[kg2][rh * 64][0];
    }

    f32x4 acc[4][4] = {};
    int kg = lane >> 4, lr = lane & 15;

    for (int k0 = 0; k0 < kLen; k0 += 64) {
#pragma unroll
        for (int i = 0; i < 8; ++i)
            load_lds16(gsrc[i] + k0, ldst[i]);
        __syncthreads();
#pragma unroll
        for (int sub = 0; sub < 2; ++sub) {
            bf16x8 af[4], bfr[4];
#pragma unroll
            for (int f = 0; f < 4; ++f) {
                af[f]  = *(const bf16x8*)&As[sub * 4 + kg][wr * 64 + f * 16 + lr][0];
                bfr[f] = *(const bf16x8*)&Bs[sub * 4 + kg][wc * 64 + f * 16 + lr][0];
            }
#pragma unroll
            for (int fm = 0; fm < 4; ++fm)
#pragma unroll
                for (int fn = 0; fn < 4; ++fn)
                    acc[fm][fn] = __builtin_amdgcn_mfma_f32_16x16x32_bf16(af[fm], bfr[fn], acc[fm][fn], 0, 0, 0);
        }
        __syncthreads();
    }

    int q4 = (lane >> 4) * 4;
    if (MODE == 0) {
#pragma unroll
        for (int fm = 0; fm < 4; ++fm)
#pragma unroll
            for (int fn = 0; fn < 4; ++fn) {
                int row = bm + wr * 64 + fm * 16 + q4;
                int col = bn + wc * 64 + fn * 16 + lr;
#pragma unroll
                for (int r = 0; r < 4; ++r)
                    Cout[((long)bz * M + row + r) * N + col] = acc[fm][fn][r];
            }
    } else {
#pragma unroll
        for (int fm = 0; fm < 4; ++fm) {
#pragma unroll
            for (int r = 0; r < 4; ++r) {
                int row = bm + wr * 64 + fm * 16 + q4 + r;
                float v = 0.f;
#pragma unroll
                for (int fn = 0; fn < 4; ++fn) {
                    int col = bn + wc * 64 + fn * 16 + lr;
                    v += acc[fm][fn][r] * zo[(long)row * N + col];
                }
                v += __shfl_xor(v, 1, 64);
                v += __shfl_xor(v, 2, 64);
                v += __shfl_xor(v, 4, 64);
                v += __shfl_xor(v, 8, 64);
                if (lr == 0) atomicAdd(out + row, v);
            }
        }
    }
}

// Combined launch: contexts (splitK=4) + ehet (splitK=8), grid (16,16,4)
__launch_bounds__(256)
__global__ void gemm_ctx_ehet(const __hip_bfloat16* __restrict__ pattB,
                              const __hip_bfloat16* __restrict__ seqT,
                              float* __restrict__ cpart,
                              const __hip_bfloat16* __restrict__ embB,
                              const __hip_bfloat16* __restrict__ WhtT,
                              float* __restrict__ ehetP)
{
    __shared__ short As[8][128][8];
    __shared__ short Bs[8][128][8];
    if (blockIdx.x < 8) {
        // contexts: M=2048, N=1024, K=2048, splitK=4 (kLen=512)
        gemm_core<0>(pattB, seqT, cpart, nullptr, nullptr,
                     NP, HID, S_LEN, S_LEN / 4, blockIdx.x, blockIdx.y, blockIdx.z, As, Bs);
    } else {
        if (blockIdx.z >= 2) return;
        // ehet: M=256, N=2048, K=1024, splitK=8 (kLen=128): 256 remapped blocks
        int u = ((blockIdx.x - 8) * 16 + blockIdx.y) * 2 + blockIdx.z;   // 0..255
        int ex = u & 15, ey = (u >> 4) & 1, ez = u >> 5;                 // ez 0..7
        gemm_core<0>(embB, WhtT, ehetP, nullptr, nullptr,
                     NE, 2 * PHID, HID, HID / 8, ex, ey, ez, As, Bs);
    }
}

template <int MODE>
__launch_bounds__(256)
__global__ void gemm_single(const __hip_bfloat16* __restrict__ A,
                            const __hip_bfloat16* __restrict__ Bt,
                            float* __restrict__ Cout,
                            const float* __restrict__ zo,
                            float* __restrict__ out,
                            int M, int N, int Kstride, int kLen)
{
    __shared__ short As[8][128][8];
    __shared__ short Bs[8][128][8];
    gemm_core<MODE>(A, Bt, Cout, zo, out, M, N, Kstride, kLen,
                    blockIdx.x, blockIdx.y, blockIdx.z, As, Bs);
}

// ---------------------------------------------------------------------------
// 5) merged reduce: blocks [0,8192): ctx 4-slice -> bf16; [8192,10240): ehet 8-slice -> f32
// ---------------------------------------------------------------------------
__global__ void reduce_both(const float* __restrict__ cpart, __hip_bfloat16* __restrict__ ctxB,
                            const float* __restrict__ ehetP, float* __restrict__ ehet)
{
    long b = blockIdx.x;
    if (b < 8192) {
        long i = b * 256 + threadIdx.x;
        const long n = (long)NP * HID;
        ctxB[i] = __float2bfloat16(cpart[i] + cpart[n + i] + cpart[2 * n + i] + cpart[3 * n + i]);
    } else {
        long i = (b - 8192) * 256 + threadIdx.x;
        const long n = (long)NE * 2 * PHID;
        float s = 0.f;
#pragma unroll
        for (int k = 0; k < 8; ++k) s += ehetP[(long)k * n + i];
        ehet[i] = s;
    }
}

// ---------------------------------------------------------------------------
// 6) zs/zo (+ out = b_bil init): folds ctxp 4-slice sum
// ---------------------------------------------------------------------------
__global__ void zs_zo_kernel(const float* __restrict__ ctxpP,  // [4][P][PH]
                             const float* __restrict__ ehet,   // [E][2PH]
                             const float* __restrict__ b_head,
                             const float* __restrict__ b_tail,
                             const int* __restrict__ pair_h,
                             const int* __restrict__ pair_t,
                             __hip_bfloat16* __restrict__ zs, float* __restrict__ zo,
                             const float* __restrict__ b_bil, float* __restrict__ out)
{
    long idx = (long)blockIdx.x * 256 + threadIdx.x;
    if (idx < NP) out[idx] = b_bil[0];
    int p = (int)(idx >> 10);
    int j = (int)(idx & (PHID - 1));
    const long n = (long)NP * PHID;
    float c = ctxpP[idx] + ctxpP[n + idx] + ctxpP[2 * n + idx] + ctxpP[3 * n + idx];
    float hs = ehet[(long)pair_h[p] * 2048 + j] + b_head[j] + c;
    float ts = ehet[(long)pair_t[p] * 2048 + 1024 + j] + b_tail[j] + c;
    zs[idx] = __float2bfloat16(tanhf(hs));
    zo[idx] = tanhf(ts);
}

// ---------------------------------------------------------------------------
// Launch
// ---------------------------------------------------------------------------
extern "C" void kernel_launch(void* const* d_in, const int* in_sizes, int n_in,
                              void* d_out, int out_size, void* d_ws, size_t ws_size,
                              hipStream_t stream)
{
    const float* seq        = (const float*)d_in[0];
    const float* attention  = (const float*)d_in[1];
    const int*   mention_idx= (const int*)  d_in[2];
    const int*   entity_ids = (const int*)  d_in[3];
    const int*   pair_h     = (const int*)  d_in[4];
    const int*   pair_t     = (const int*)  d_in[5];
    const float* W_head     = (const float*)d_in[6];
    const float* b_head     = (const float*)d_in[7];
    const float* W_tail     = (const float*)d_in[8];
    const float* b_tail     = (const float*)d_in[9];
    const float* W_ctx      = (const float*)d_in[10];
    const float* W_bil      = (const float*)d_in[11];
    const float* b_bil      = (const float*)d_in[12];
    float* out = (float*)d_out;

    // ---- workspace (MB offsets) ----
    char* w = (char*)d_ws;
    __hip_bfloat16* seqT  = (__hip_bfloat16*)(w + 0);           // [H][S]      4 MB
    __hip_bfloat16* WctxT = (__hip_bfloat16*)(w + (4l << 20));  // [PH][H]     2 MB
    __hip_bfloat16* WhtT  = (__hip_bfloat16*)(w + (6l << 20));  // [2PH][H]    4 MB
    __hip_bfloat16* WbilT = (__hip_bfloat16*)(w + (10l << 20)); // [PH][PH]    2 MB
    __hip_bfloat16* embB  = (__hip_bfloat16*)(w + (12l << 20)); // [E][H]      0.5 MB
    __hip_bfloat16* eaB   = (__hip_bfloat16*)(w + (13l << 20)); // [E][16][S]  16 MB
    __hip_bfloat16* pattB = (__hip_bfloat16*)(w + (29l << 20)); // [P][S]      8 MB
    __hip_bfloat16* ctxB  = (__hip_bfloat16*)(w + (37l << 20)); // [P][H]      4 MB
    __hip_bfloat16* zsB   = (__hip_bfloat16*)(w + (41l << 20)); // [P][PH]     4 MB
    float* zo    = (float*)(w + (45l << 20));                   // [P][PH]     8 MB
    float* cpart = (float*)(w + (53l << 20));                   // [4][P][H]   32 MB
    float* ctxpP = (float*)(w + (85l << 20));                   // [4][P][PH]  32 MB
    float* ehetP = (float*)(w + (117l << 20));                  // [8][E][2PH] 16 MB
    float* ehet  = (float*)(w + (133l << 20));                  // [E][2PH]    2 MB

    // ---- 1) prep (seq + weights) + entity emb/att, one launch ----
    prep_ent_kernel<<<10496, 256, 0, stream>>>(seq, attention, W_ctx, W_head, W_tail, W_bil,
                                               mention_idx, entity_ids,
                                               seqT, WctxT, WhtT, WhtT + (long)PHID * HID, WbilT,
                                               (uint2*)eaB, embB);

    // ---- 2) pair attention ----
    pair_att_kernel<<<NP, 256, 0, stream>>>((const uint4*)eaB, pair_h, pair_t, (uint4*)pattB);

    // ---- 3) contexts (splitK=4) + ehet (splitK=8) in one launch ----
    gemm_ctx_ehet<<<dim3(16, 16, 4), 256, 0, stream>>>(pattB, seqT, cpart, embB, WhtT, ehetP);

    // ---- 4) merged reduce: ctxB (bf16) + ehet (f32) ----
    reduce_both<<<10240, 256, 0, stream>>>(cpart, ctxB, ehetP, ehet);

    // ---- 5) ctxp partials = contexts @ W_ctx, splitK=4 ----
    gemm_single<0><<<dim3(8, 16, 4), 256, 0, stream>>>(ctxB, WctxT, ctxpP, nullptr, nullptr,
                                                       NP, PHID, HID, HID / 4);

    // ---- 6) zs/zo + out=b_bil ----
    zs_zo_kernel<<<8192, 256, 0, stream>>>(ctxpP, ehet, b_head, b_tail, pair_h, pair_t,
                                           zsB, zo, b_bil, out);

    // ---- 7) fused bilinear, splitK=4 ----
    gemm_single<2><<<dim3(8, 16, 4), 256, 0, stream>>>(zsB, WbilT, nullptr, zo, out,
                                                       NP, PHID, HID, HID / 4);
}

// Round 7
// 145.774 us; speedup vs baseline: 1.4502x; 1.2349x over previous
//
#include <hip/hip_runtime.h>
#include <hip/hip_bf16.h>
#include <math.h>
#include <stdint.h>

// Problem constants
#define S_LEN  2048
#define HID    1024
#define NHEADS 16
#define NE     256
#define NMEN   1024
#define NP     2048
#define PHID   1024

typedef __attribute__((ext_vector_type(8))) short bf16x8;
typedef __attribute__((ext_vector_type(4))) float f32x4;
typedef unsigned int uint;

// ---------------------------------------------------------------------------
// Helpers
// ---------------------------------------------------------------------------
__device__ inline void seg_bounds(const int* __restrict__ entity_ids, int e,
                                  int& start, int& end) {
    int lo = 0, hi = NMEN;
    while (lo < hi) { int mid = (lo + hi) >> 1; if (entity_ids[mid] < e) lo = mid + 1; else hi = mid; }
    start = lo;
    hi = NMEN;
    while (lo < hi) { int mid = (lo + hi) >> 1; if (entity_ids[mid] <= e) lo = mid + 1; else hi = mid; }
    end = lo;
}

__device__ __forceinline__ void load_lds16(const void* g, void* l) {
    __builtin_amdgcn_global_load_lds(
        (const __attribute__((address_space(1))) uint32_t*)g,
        (__attribute__((address_space(3))) uint32_t*)l,
        16, 0, 0);
}

__device__ __forceinline__ float bflo(uint u) { return __uint_as_float(u << 16); }
__device__ __forceinline__ float bfhi(uint u) { return __uint_as_float(u & 0xffff0000u); }
__device__ __forceinline__ uint pk2(float a, float b) {
    __hip_bfloat16 ha = __float2bfloat16(a), hb = __float2bfloat16(b);
    unsigned short ua = *(unsigned short*)&ha, ub = *(unsigned short*)&hb;
    return (uint)ua | ((uint)ub << 16);
}

// ---------------------------------------------------------------------------
// L1) Merged prep + entity kernel, flat grid 9472 blocks:
//   [0,1024)      seq fp32 -> bf16 cast (seqB, row-major)
//   [1024,5120)   4 weight transposes -> bf16
//   [5120,9472)   entity: e = t&255, role = t>>8 (0..15: att head; 16: emb)
// ---------------------------------------------------------------------------
__global__ void prep_ent_kernel(const float* __restrict__ seq,
                                const float* __restrict__ attention,
                                const float* __restrict__ w0, const float* __restrict__ w1,
                                const float* __restrict__ w2, const float* __restrict__ w3,
                                const int* __restrict__ mention_idx,
                                const int* __restrict__ entity_ids,
                                __hip_bfloat16* __restrict__ seqB,
                                __hip_bfloat16* __restrict__ o0, __hip_bfloat16* __restrict__ o1,
                                __hip_bfloat16* __restrict__ o2, __hip_bfloat16* __restrict__ o3,
                                uint2* __restrict__ eaB,
                                __hip_bfloat16* __restrict__ ent_emb)
{
    __shared__ float tbuf[32][33];
    __shared__ int sb[2];
    int id = blockIdx.x;
    if (id < 1024) {
        // cast 8 floats/thread
        long i = (long)id * 256 + threadIdx.x;
        const float4* in4 = (const float4*)seq;
        float4 a = in4[2 * i], b = in4[2 * i + 1];
        uint4 o;
        o.x = pk2(a.x, a.y); o.y = pk2(a.z, a.w);
        o.z = pk2(b.x, b.y); o.w = pk2(b.z, b.w);
        ((uint4*)seqB)[i] = o;
        return;
    }
    if (id < 5120) {
        int t = id - 1024;
        int z = t >> 10;
        const float* in = (z == 0) ? w0 : (z == 1) ? w1 : (z == 2) ? w2 : w3;
        __hip_bfloat16* out = (z == 0) ? o0 : (z == 1) ? o1 : (z == 2) ? o2 : o3;
        int r0 = ((t >> 5) & 31) * 32, c0 = (t & 31) * 32;
        int j = threadIdx.x & 31, i0 = threadIdx.x >> 5;
        for (int i = i0; i < 32; i += 8)
            tbuf[i][j] = in[(long)(r0 + i) * 1024 + c0 + j];
        __syncthreads();
        for (int i = i0; i < 32; i += 8)
            out[(long)(c0 + i) * 1024 + r0 + j] = __float2bfloat16(tbuf[j][i]);
        return;
    }
    // entity work
    int t = id - 5120;
    int e = t & 255, role = t >> 8;
    if (threadIdx.x == 0) { int s, tt; seg_bounds(entity_ids, e, s, tt); sb[0] = s; sb[1] = tt; }
    __syncthreads();
    int start = sb[0], end = sb[1];

    if (role < 16) {
        const float4* att4 = (const float4*)attention;
        int h = role;
        float inv = 1.f / fmaxf((float)(end - start), 1.f);
        for (int s4 = threadIdx.x; s4 < S_LEN / 4; s4 += 256) {
            float ax = 0.f, ay = 0.f, az = 0.f, aw = 0.f;
            for (int i = start; i < end; ++i) {
                float4 v = att4[((long)h * S_LEN + mention_idx[i]) * (S_LEN / 4) + s4];
                ax += v.x; ay += v.y; az += v.z; aw += v.w;
            }
            uint2 o; o.x = pk2(ax * inv, ay * inv); o.y = pk2(az * inv, aw * inv);
            eaB[((long)e * NHEADS + h) * (S_LEN / 4) + s4] = o;
        }
    } else {
        const float4* seq4 = (const float4*)seq;
        int col4 = threadIdx.x;
        uint2 o;
        if (end <= start) {
            o.x = 0; o.y = 0;
            ((uint2*)ent_emb)[(long)e * 256 + col4] = o;
            return;
        }
        float mx = -INFINITY, my = -INFINITY, mz = -INFINITY, mw = -INFINITY;
        for (int i = start; i < end; ++i) {
            float4 v = seq4[(long)mention_idx[i] * 256 + col4];
            mx = fmaxf(mx, v.x); my = fmaxf(my, v.y); mz = fmaxf(mz, v.z); mw = fmaxf(mw, v.w);
        }
        float sx = 0.f, sy = 0.f, sz = 0.f, sw = 0.f;
        for (int i = start; i < end; ++i) {
            float4 v = seq4[(long)mention_idx[i] * 256 + col4];
            sx += expf(v.x - mx); sy += expf(v.y - my); sz += expf(v.z - mz); sw += expf(v.w - mw);
        }
        o.x = pk2(mx + logf(sx), my + logf(sy));
        o.y = pk2(mz + logf(sz), mw + logf(sw));
        ((uint2*)ent_emb)[(long)e * 256 + col4] = o;
    }
}

// ---------------------------------------------------------------------------
// bf16 MFMA GEMM core: 128x128 tile, BK=64 (32 KB LDS), 4 waves (2x2).
//    MODE 0: Cout fp32 partial at slice bz
//    MODE 1: Cout bf16 direct (no split)
//    MODE 2: fused bilinear: atomicAdd(out+row, sum_col acc*zo[row][col])
// ---------------------------------------------------------------------------
template <int MODE>
__device__ __forceinline__ void gemm_core(
    const __hip_bfloat16* __restrict__ A,
    const __hip_bfloat16* __restrict__ Bt,
    void* __restrict__ Cout, const float* __restrict__ zo, float* __restrict__ out,
    int M, int N, int Kstride, int kLen,
    int bx, int by, int bz,
    short (*As)[128][8], short (*Bs)[128][8])
{
    int tid = threadIdx.x;
    int lane = tid & 63, wid = tid >> 6;
    int wr = wid >> 1, wc = wid & 1;
    int bm = by * 128, bn = bx * 128;
    int kBeg = bz * kLen;

    const __hip_bfloat16* gsrc[8];
    void* ldst[8];
#pragma unroll
    for (int i = 0; i < 8; ++i) {
        int c = wid * 8 + i;
        int isA = (c < 16) ? 1 : 0;
        int cc = isA ? c : c - 16;
        int kg2 = cc >> 1, rh = cc & 1;
        gsrc[i] = (isA ? A + (long)(bm + rh * 64 + lane) * Kstride
                       : Bt + (long)(bn + rh * 64 + lane) * Kstride) + kBeg + kg2 * 8;
        ldst[i] = isA ? (void*)&As[kg2][rh * 64][0] : (void*)&Bs[kg2][rh * 64][0];
    }

    f32x4 acc[4][4] = {};
    int kg = lane >> 4, lr = lane & 15;

    for (int k0 = 0; k0 < kLen; k0 += 64) {
#pragma unroll
        for (int i = 0; i < 8; ++i)
            load_lds16(gsrc[i] + k0, ldst[i]);
        __syncthreads();
#pragma unroll
        for (int sub = 0; sub < 2; ++sub) {
            bf16x8 af[4], bfr[4];
#pragma unroll
            for (int f = 0; f < 4; ++f) {
                af[f]  = *(const bf16x8*)&As[sub * 4 + kg][wr * 64 + f * 16 + lr][0];
                bfr[f] = *(const bf16x8*)&Bs[sub * 4 + kg][wc * 64 + f * 16 + lr][0];
            }
#pragma unroll
            for (int fm = 0; fm < 4; ++fm)
#pragma unroll
                for (int fn = 0; fn < 4; ++fn)
                    acc[fm][fn] = __builtin_amdgcn_mfma_f32_16x16x32_bf16(af[fm], bfr[fn], acc[fm][fn], 0, 0, 0);
        }
        __syncthreads();
    }

    int q4 = (lane >> 4) * 4;
    if (MODE == 0) {
#pragma unroll
        for (int fm = 0; fm < 4; ++fm)
#pragma unroll
            for (int fn = 0; fn < 4; ++fn) {
                int row = bm + wr * 64 + fm * 16 + q4;
                int col = bn + wc * 64 + fn * 16 + lr;
#pragma unroll
                for (int r = 0; r < 4; ++r)
                    ((float*)Cout)[((long)bz * M + row + r) * N + col] = acc[fm][fn][r];
            }
    } else if (MODE == 1) {
#pragma unroll
        for (int fm = 0; fm < 4; ++fm)
#pragma unroll
            for (int fn = 0; fn < 4; ++fn) {
                int row = bm + wr * 64 + fm * 16 + q4;
                int col = bn + wc * 64 + fn * 16 + lr;
#pragma unroll
                for (int r = 0; r < 4; ++r)
                    ((__hip_bfloat16*)Cout)[(long)(row + r) * N + col] = __float2bfloat16(acc[fm][fn][r]);
            }
    } else {
#pragma unroll
        for (int fm = 0; fm < 4; ++fm) {
#pragma unroll
            for (int r = 0; r < 4; ++r) {
                int row = bm + wr * 64 + fm * 16 + q4 + r;
                float v = 0.f;
#pragma unroll
                for (int fn = 0; fn < 4; ++fn) {
                    int col = bn + wc * 64 + fn * 16 + lr;
                    v += acc[fm][fn][r] * zo[(long)row * N + col];
                }
                v += __shfl_xor(v, 1, 64);
                v += __shfl_xor(v, 2, 64);
                v += __shfl_xor(v, 4, 64);
                v += __shfl_xor(v, 8, 64);
                if (lr == 0) atomicAdd(out + row, v);
            }
        }
    }
}

// ---------------------------------------------------------------------------
// L2) Merged: seqW GEMM (128 blocks, MODE 1) + ehet GEMM (128 blocks, splitK=4)
//     + pair attention (2048 blocks). Compute blocks first for overlap.
// ---------------------------------------------------------------------------
__launch_bounds__(256)
__global__ void pair_seqw_ehet(const __hip_bfloat16* __restrict__ WctxT,
                               const __hip_bfloat16* __restrict__ seqB,
                               __hip_bfloat16* __restrict__ seqWT,
                               const __hip_bfloat16* __restrict__ embB,
                               const __hip_bfloat16* __restrict__ WhtT,
                               float* __restrict__ ehetP,
                               const uint4* __restrict__ ea,
                               const int* __restrict__ pair_h,
                               const int* __restrict__ pair_t,
                               uint4* __restrict__ patt)
{
    __shared__ short As[8][128][8];
    __shared__ short Bs[8][128][8];
    int id = blockIdx.x;
    if (id < 128) {
        // seqWT[j][s] = (seq@W_ctx)[s][j] : A=WctxT [1024][1024], Bt=seqB [2048][1024]
        // M=1024, N=2048, K=1024, full K, bf16 direct
        gemm_core<1>(WctxT, seqB, seqWT, nullptr, nullptr,
                     PHID, S_LEN, HID, HID, id & 15, id >> 4, 0, As, Bs);
        return;
    }
    if (id < 256) {
        // ehet: A=embB [256][1024], Bt=WhtT [2048][1024], M=256,N=2048,K=1024, splitK=4
        int u = id - 128;
        gemm_core<0>(embB, WhtT, ehetP, nullptr, nullptr,
                     NE, 2 * PHID, HID, HID / 4, u & 15, (u >> 4) & 1, u >> 5, As, Bs);
        return;
    }
    // pair attention
    __shared__ float wsum[4];
    int p = id - 256;
    long bh = (long)pair_h[p] * NHEADS * (S_LEN / 8);
    long bt = (long)pair_t[p] * NHEADS * (S_LEN / 8);
    int s8 = threadIdx.x;
    float a0 = 0, a1 = 0, a2 = 0, a3 = 0, a4 = 0, a5 = 0, a6 = 0, a7 = 0;
#pragma unroll
    for (int h = 0; h < NHEADS; ++h) {
        uint4 xa = ea[bh + h * (S_LEN / 8) + s8];
        uint4 xb = ea[bt + h * (S_LEN / 8) + s8];
        a0 += bflo(xa.x) * bflo(xb.x); a1 += bfhi(xa.x) * bfhi(xb.x);
        a2 += bflo(xa.y) * bflo(xb.y); a3 += bfhi(xa.y) * bfhi(xb.y);
        a4 += bflo(xa.z) * bflo(xb.z); a5 += bfhi(xa.z) * bfhi(xb.z);
        a6 += bflo(xa.w) * bflo(xb.w); a7 += bfhi(xa.w) * bfhi(xb.w);
    }
    float psum = a0 + a1 + a2 + a3 + a4 + a5 + a6 + a7;
#pragma unroll
    for (int off = 32; off > 0; off >>= 1)
        psum += __shfl_down(psum, off, 64);
    int lane = threadIdx.x & 63, wid = threadIdx.x >> 6;
    if (lane == 0) wsum[wid] = psum;
    __syncthreads();
    float inv = 1.f / (wsum[0] + wsum[1] + wsum[2] + wsum[3] + 1e-6f);
    uint4 o;
    o.x = pk2(a0 * inv, a1 * inv); o.y = pk2(a2 * inv, a3 * inv);
    o.z = pk2(a4 * inv, a5 * inv); o.w = pk2(a6 * inv, a7 * inv);
    patt[(long)p * (S_LEN / 8) + s8] = o;
}

// ---------------------------------------------------------------------------
// L3) ctxp partials = pattB @ seqWT^T : M=2048, N=1024, K=2048, splitK=4
// ---------------------------------------------------------------------------
template <int MODE>
__launch_bounds__(256)
__global__ void gemm_single(const __hip_bfloat16* __restrict__ A,
                            const __hip_bfloat16* __restrict__ Bt,
                            void* __restrict__ Cout,
                            const float* __restrict__ zo,
                            float* __restrict__ out,
                            int M, int N, int Kstride, int kLen)
{
    __shared__ short As[8][128][8];
    __shared__ short Bs[8][128][8];
    gemm_core<MODE>(A, Bt, Cout, zo, out, M, N, Kstride, kLen,
                    blockIdx.x, blockIdx.y, blockIdx.z, As, Bs);
}

// ---------------------------------------------------------------------------
// L4) zs/zo (+ out = b_bil init): folds ctxp 4-slice sum + ehet 4-slice gather
// ---------------------------------------------------------------------------
__global__ void zs_zo_kernel(const float* __restrict__ ctxpP,  // [4][P][PH]
                             const float* __restrict__ ehetP,  // [4][E][2PH]
                             const float* __restrict__ b_head,
                             const float* __restrict__ b_tail,
                             const int* __restrict__ pair_h,
                             const int* __restrict__ pair_t,
                             __hip_bfloat16* __restrict__ zs, float* __restrict__ zo,
                             const float* __restrict__ b_bil, float* __restrict__ out)
{
    long idx = (long)blockIdx.x * 256 + threadIdx.x;
    if (idx < NP) out[idx] = b_bil[0];
    int p = (int)(idx >> 10);
    int j = (int)(idx & (PHID - 1));
    const long n = (long)NP * PHID;
    float c = ctxpP[idx] + ctxpP[n + idx] + ctxpP[2 * n + idx] + ctxpP[3 * n + idx];
    const long m = (long)NE * 2 * PHID;
    long hb = (long)pair_h[p] * 2048 + j;
    long tb = (long)pair_t[p] * 2048 + 1024 + j;
    float hs = b_head[j] + c, ts = b_tail[j] + c;
#pragma unroll
    for (int s = 0; s < 4; ++s) {
        hs += ehetP[s * m + hb];
        ts += ehetP[s * m + tb];
    }
    zs[idx] = __float2bfloat16(tanhf(hs));
    zo[idx] = tanhf(ts);
}

// ---------------------------------------------------------------------------
// Launch
// ---------------------------------------------------------------------------
extern "C" void kernel_launch(void* const* d_in, const int* in_sizes, int n_in,
                              void* d_out, int out_size, void* d_ws, size_t ws_size,
                              hipStream_t stream)
{
    const float* seq        = (const float*)d_in[0];
    const float* attention  = (const float*)d_in[1];
    const int*   mention_idx= (const int*)  d_in[2];
    const int*   entity_ids = (const int*)  d_in[3];
    const int*   pair_h     = (const int*)  d_in[4];
    const int*   pair_t     = (const int*)  d_in[5];
    const float* W_head     = (const float*)d_in[6];
    const float* b_head     = (const float*)d_in[7];
    const float* W_tail     = (const float*)d_in[8];
    const float* b_tail     = (const float*)d_in[9];
    const float* W_ctx      = (const float*)d_in[10];
    const float* W_bil      = (const float*)d_in[11];
    const float* b_bil      = (const float*)d_in[12];
    float* out = (float*)d_out;

    // ---- workspace (MB offsets) ----
    char* w = (char*)d_ws;
    __hip_bfloat16* seqB  = (__hip_bfloat16*)(w + 0);           // [S][H]      4 MB
    __hip_bfloat16* WctxT = (__hip_bfloat16*)(w + (4l << 20));  // [PH][H]     2 MB
    __hip_bfloat16* WhtT  = (__hip_bfloat16*)(w + (6l << 20));  // [2PH][H]    4 MB
    __hip_bfloat16* WbilT = (__hip_bfloat16*)(w + (10l << 20)); // [PH][PH]    2 MB
    __hip_bfloat16* embB  = (__hip_bfloat16*)(w + (12l << 20)); // [E][H]      0.5 MB
    __hip_bfloat16* eaB   = (__hip_bfloat16*)(w + (13l << 20)); // [E][16][S]  16 MB
    __hip_bfloat16* pattB = (__hip_bfloat16*)(w + (29l << 20)); // [P][S]      8 MB
    __hip_bfloat16* seqWT = (__hip_bfloat16*)(w + (37l << 20)); // [PH][S]     4 MB
    __hip_bfloat16* zsB   = (__hip_bfloat16*)(w + (41l << 20)); // [P][PH]     4 MB
    float* zo    = (float*)(w + (45l << 20));                   // [P][PH]     8 MB
    float* ctxpP = (float*)(w + (53l << 20));                   // [4][P][PH]  32 MB
    float* ehetP = (float*)(w + (85l << 20));                   // [4][E][2PH] 8 MB

    // ---- L1: prep (cast + transposes) + entity emb/att ----
    prep_ent_kernel<<<9472, 256, 0, stream>>>(seq, attention, W_ctx, W_head, W_tail, W_bil,
                                              mention_idx, entity_ids,
                                              seqB, WctxT, WhtT, WhtT + (long)PHID * HID, WbilT,
                                              (uint2*)eaB, embB);

    // ---- L2: seqW GEMM + ehet GEMM + pair attention, one launch ----
    pair_seqw_ehet<<<2304, 256, 0, stream>>>(WctxT, seqB, seqWT, embB, WhtT, ehetP,
                                             (const uint4*)eaB, pair_h, pair_t, (uint4*)pattB);

    // ---- L3: ctxp partials = pattB @ seqWT^T, splitK=4 ----
    gemm_single<0><<<dim3(8, 16, 4), 256, 0, stream>>>(pattB, seqWT, ctxpP, nullptr, nullptr,
                                                       NP, PHID, S_LEN, S_LEN / 4);

    // ---- L4: zs/zo + out=b_bil ----
    zs_zo_kernel<<<8192, 256, 0, stream>>>(ctxpP, ehetP, b_head, b_tail, pair_h, pair_t,
                                           zsB, zo, b_bil, out);

    // ---- L5: fused bilinear, splitK=2 ----
    gemm_single<2><<<dim3(8, 16, 2), 256, 0, stream>>>(zsB, WbilT, nullptr, zo, out,
                                                       NP, PHID, HID, HID / 2);
}

// Round 8
// 139.827 us; speedup vs baseline: 1.5119x; 1.0425x over previous
//
#include <hip/hip_runtime.h>
#include <hip/hip_bf16.h>
#include <math.h>
#include <stdint.h>

// Problem constants
#define S_LEN  2048
#define HID    1024
#define NHEADS 16
#define NE     256
#define NMEN   1024
#define NP     2048
#define PHID   1024

typedef __attribute__((ext_vector_type(8))) short bf16x8;
typedef __attribute__((ext_vector_type(4))) float f32x4;
typedef unsigned int uint;

// ---------------------------------------------------------------------------
// Helpers
// ---------------------------------------------------------------------------
__device__ inline void seg_bounds(const int* __restrict__ entity_ids, int e,
                                  int& start, int& end) {
    int lo = 0, hi = NMEN;
    while (lo < hi) { int mid = (lo + hi) >> 1; if (entity_ids[mid] < e) lo = mid + 1; else hi = mid; }
    start = lo;
    hi = NMEN;
    while (lo < hi) { int mid = (lo + hi) >> 1; if (entity_ids[mid] <= e) lo = mid + 1; else hi = mid; }
    end = lo;
}

__device__ __forceinline__ void load_lds16(const void* g, void* l) {
    __builtin_amdgcn_global_load_lds(
        (const __attribute__((address_space(1))) uint32_t*)g,
        (__attribute__((address_space(3))) uint32_t*)l,
        16, 0, 0);
}

__device__ __forceinline__ float bflo(uint u) { return __uint_as_float(u << 16); }
__device__ __forceinline__ float bfhi(uint u) { return __uint_as_float(u & 0xffff0000u); }
__device__ __forceinline__ uint pk2(float a, float b) {
    __hip_bfloat16 ha = __float2bfloat16(a), hb = __float2bfloat16(b);
    unsigned short ua = *(unsigned short*)&ha, ub = *(unsigned short*)&hb;
    return (uint)ua | ((uint)ub << 16);
}

// ---------------------------------------------------------------------------
// L1) Merged prep + entity kernel, flat grid 8960 blocks:
//   [0,1024)      seq fp32 -> bf16 cast (row-major)
//   [1024,4096)   3 weight transposes (W_ctx, W_head, W_tail) -> bf16
//   [4096,4608)   W_bil fp32 -> bf16 cast (row-major)
//   [4608,8960)   entity: e = t&255, role = t>>8 (0..15: att head; 16: emb)
// ---------------------------------------------------------------------------
__global__ void prep_ent_kernel(const float* __restrict__ seq,
                                const float* __restrict__ attention,
                                const float* __restrict__ w0, const float* __restrict__ w1,
                                const float* __restrict__ w2, const float* __restrict__ wbil,
                                const int* __restrict__ mention_idx,
                                const int* __restrict__ entity_ids,
                                __hip_bfloat16* __restrict__ seqB,
                                __hip_bfloat16* __restrict__ o0, __hip_bfloat16* __restrict__ o1,
                                __hip_bfloat16* __restrict__ o2, __hip_bfloat16* __restrict__ obil,
                                uint2* __restrict__ eaB,
                                __hip_bfloat16* __restrict__ ent_emb)
{
    __shared__ float tbuf[32][33];
    __shared__ int sb[2];
    int id = blockIdx.x;
    if (id < 1024) {
        long i = (long)id * 256 + threadIdx.x;
        const float4* in4 = (const float4*)seq;
        float4 a = in4[2 * i], b = in4[2 * i + 1];
        uint4 o;
        o.x = pk2(a.x, a.y); o.y = pk2(a.z, a.w);
        o.z = pk2(b.x, b.y); o.w = pk2(b.z, b.w);
        ((uint4*)seqB)[i] = o;
        return;
    }
    if (id < 4096) {
        int t = id - 1024;
        int z = t >> 10;
        const float* in = (z == 0) ? w0 : (z == 1) ? w1 : w2;
        __hip_bfloat16* out = (z == 0) ? o0 : (z == 1) ? o1 : o2;
        int r0 = ((t >> 5) & 31) * 32, c0 = (t & 31) * 32;
        int j = threadIdx.x & 31, i0 = threadIdx.x >> 5;
        for (int i = i0; i < 32; i += 8)
            tbuf[i][j] = in[(long)(r0 + i) * 1024 + c0 + j];
        __syncthreads();
        for (int i = i0; i < 32; i += 8)
            out[(long)(c0 + i) * 1024 + r0 + j] = __float2bfloat16(tbuf[j][i]);
        return;
    }
    if (id < 4608) {
        long i = (long)(id - 4096) * 256 + threadIdx.x;
        const float4* in4 = (const float4*)wbil;
        float4 a = in4[2 * i], b = in4[2 * i + 1];
        uint4 o;
        o.x = pk2(a.x, a.y); o.y = pk2(a.z, a.w);
        o.z = pk2(b.x, b.y); o.w = pk2(b.z, b.w);
        ((uint4*)obil)[i] = o;
        return;
    }
    // entity work
    int t = id - 4608;
    int e = t & 255, role = t >> 8;
    if (threadIdx.x == 0) { int s, tt; seg_bounds(entity_ids, e, s, tt); sb[0] = s; sb[1] = tt; }
    __syncthreads();
    int start = sb[0], end = sb[1];

    if (role < 16) {
        const float4* att4 = (const float4*)attention;
        int h = role;
        float inv = 1.f / fmaxf((float)(end - start), 1.f);
        for (int s4 = threadIdx.x; s4 < S_LEN / 4; s4 += 256) {
            float ax = 0.f, ay = 0.f, az = 0.f, aw = 0.f;
            for (int i = start; i < end; ++i) {
                float4 v = att4[((long)h * S_LEN + mention_idx[i]) * (S_LEN / 4) + s4];
                ax += v.x; ay += v.y; az += v.z; aw += v.w;
            }
            uint2 o; o.x = pk2(ax * inv, ay * inv); o.y = pk2(az * inv, aw * inv);
            eaB[((long)e * NHEADS + h) * (S_LEN / 4) + s4] = o;
        }
    } else {
        const float4* seq4 = (const float4*)seq;
        int col4 = threadIdx.x;
        uint2 o;
        if (end <= start) {
            o.x = 0; o.y = 0;
            ((uint2*)ent_emb)[(long)e * 256 + col4] = o;
            return;
        }
        float mx = -INFINITY, my = -INFINITY, mz = -INFINITY, mw = -INFINITY;
        for (int i = start; i < end; ++i) {
            float4 v = seq4[(long)mention_idx[i] * 256 + col4];
            mx = fmaxf(mx, v.x); my = fmaxf(my, v.y); mz = fmaxf(mz, v.z); mw = fmaxf(mw, v.w);
        }
        float sx = 0.f, sy = 0.f, sz = 0.f, sw = 0.f;
        for (int i = start; i < end; ++i) {
            float4 v = seq4[(long)mention_idx[i] * 256 + col4];
            sx += expf(v.x - mx); sy += expf(v.y - my); sz += expf(v.z - mz); sw += expf(v.w - mw);
        }
        o.x = pk2(mx + logf(sx), my + logf(sy));
        o.y = pk2(mz + logf(sz), mw + logf(sw));
        ((uint2*)ent_emb)[(long)e * 256 + col4] = o;
    }
}

// ---------------------------------------------------------------------------
// bf16 MFMA GEMM core: 128x128 tile, BK=64 (32 KB LDS), 4 waves (2x2).
//    MODE 0: fp32 partial at slice bz
//    MODE 1: bf16 direct (no split)
//    MODE 2: fused bilinear: atomicAdd(out+row, sum_col acc*bf16(zvec)[row][col])
//    MODE 3: bf16 partial at slice bz
// ---------------------------------------------------------------------------
template <int MODE>
__device__ __forceinline__ void gemm_core(
    const __hip_bfloat16* __restrict__ A,
    const __hip_bfloat16* __restrict__ Bt,
    void* __restrict__ Cout, const __hip_bfloat16* __restrict__ zvec, float* __restrict__ out,
    int M, int N, int Kstride, int kLen,
    int bx, int by, int bz,
    short (*As)[128][8], short (*Bs)[128][8])
{
    int tid = threadIdx.x;
    int lane = tid & 63, wid = tid >> 6;
    int wr = wid >> 1, wc = wid & 1;
    int bm = by * 128, bn = bx * 128;
    int kBeg = bz * kLen;

    const __hip_bfloat16* gsrc[8];
    void* ldst[8];
#pragma unroll
    for (int i = 0; i < 8; ++i) {
        int c = wid * 8 + i;
        int isA = (c < 16) ? 1 : 0;
        int cc = isA ? c : c - 16;
        int kg2 = cc >> 1, rh = cc & 1;
        gsrc[i] = (isA ? A + (long)(bm + rh * 64 + lane) * Kstride
                       : Bt + (long)(bn + rh * 64 + lane) * Kstride) + kBeg + kg2 * 8;
        ldst[i] = isA ? (void*)&As[kg2][rh * 64][0] : (void*)&Bs[kg2][rh * 64][0];
    }

    f32x4 acc[4][4] = {};
    int kg = lane >> 4, lr = lane & 15;

    for (int k0 = 0; k0 < kLen; k0 += 64) {
#pragma unroll
        for (int i = 0; i < 8; ++i)
            load_lds16(gsrc[i] + k0, ldst[i]);
        __syncthreads();
#pragma unroll
        for (int sub = 0; sub < 2; ++sub) {
            bf16x8 af[4], bfr[4];
#pragma unroll
            for (int f = 0; f < 4; ++f) {
                af[f]  = *(const bf16x8*)&As[sub * 4 + kg][wr * 64 + f * 16 + lr][0];
                bfr[f] = *(const bf16x8*)&Bs[sub * 4 + kg][wc * 64 + f * 16 + lr][0];
            }
#pragma unroll
            for (int fm = 0; fm < 4; ++fm)
#pragma unroll
                for (int fn = 0; fn < 4; ++fn)
                    acc[fm][fn] = __builtin_amdgcn_mfma_f32_16x16x32_bf16(af[fm], bfr[fn], acc[fm][fn], 0, 0, 0);
        }
        __syncthreads();
    }

    int q4 = (lane >> 4) * 4;
    if (MODE == 0) {
#pragma unroll
        for (int fm = 0; fm < 4; ++fm)
#pragma unroll
            for (int fn = 0; fn < 4; ++fn) {
                int row = bm + wr * 64 + fm * 16 + q4;
                int col = bn + wc * 64 + fn * 16 + lr;
#pragma unroll
                for (int r = 0; r < 4; ++r)
                    ((float*)Cout)[((long)bz * M + row + r) * N + col] = acc[fm][fn][r];
            }
    } else if (MODE == 1) {
#pragma unroll
        for (int fm = 0; fm < 4; ++fm)
#pragma unroll
            for (int fn = 0; fn < 4; ++fn) {
                int row = bm + wr * 64 + fm * 16 + q4;
                int col = bn + wc * 64 + fn * 16 + lr;
#pragma unroll
                for (int r = 0; r < 4; ++r)
                    ((__hip_bfloat16*)Cout)[(long)(row + r) * N + col] = __float2bfloat16(acc[fm][fn][r]);
            }
    } else if (MODE == 3) {
#pragma unroll
        for (int fm = 0; fm < 4; ++fm)
#pragma unroll
            for (int fn = 0; fn < 4; ++fn) {
                int row = bm + wr * 64 + fm * 16 + q4;
                int col = bn + wc * 64 + fn * 16 + lr;
#pragma unroll
                for (int r = 0; r < 4; ++r)
                    ((__hip_bfloat16*)Cout)[((long)bz * M + row + r) * N + col] = __float2bfloat16(acc[fm][fn][r]);
            }
    } else {
#pragma unroll
        for (int fm = 0; fm < 4; ++fm) {
#pragma unroll
            for (int r = 0; r < 4; ++r) {
                int row = bm + wr * 64 + fm * 16 + q4 + r;
                float v = 0.f;
#pragma unroll
                for (int fn = 0; fn < 4; ++fn) {
                    int col = bn + wc * 64 + fn * 16 + lr;
                    v += acc[fm][fn][r] * __bfloat162float(zvec[(long)row * N + col]);
                }
                v += __shfl_xor(v, 1, 64);
                v += __shfl_xor(v, 2, 64);
                v += __shfl_xor(v, 4, 64);
                v += __shfl_xor(v, 8, 64);
                if (lr == 0) atomicAdd(out + row, v);
            }
        }
    }
}

// ---------------------------------------------------------------------------
// L2) Merged: seqW GEMM (128 blocks, MODE 1) + ehet GEMM (128 blocks, splitK=4)
//     + pair attention (2048 blocks). Compute blocks first for overlap.
// ---------------------------------------------------------------------------
__launch_bounds__(256)
__global__ void pair_seqw_ehet(const __hip_bfloat16* __restrict__ WctxT,
                               const __hip_bfloat16* __restrict__ seqB,
                               __hip_bfloat16* __restrict__ seqWT,
                               const __hip_bfloat16* __restrict__ embB,
                               const __hip_bfloat16* __restrict__ WhtT,
                               float* __restrict__ ehetP,
                               const uint4* __restrict__ ea,
                               const int* __restrict__ pair_h,
                               const int* __restrict__ pair_t,
                               uint4* __restrict__ patt)
{
    __shared__ short As[8][128][8];
    __shared__ short Bs[8][128][8];
    int id = blockIdx.x;
    if (id < 128) {
        gemm_core<1>(WctxT, seqB, seqWT, nullptr, nullptr,
                     PHID, S_LEN, HID, HID, id & 15, id >> 4, 0, As, Bs);
        return;
    }
    if (id < 256) {
        int u = id - 128;
        gemm_core<0>(embB, WhtT, ehetP, nullptr, nullptr,
                     NE, 2 * PHID, HID, HID / 4, u & 15, (u >> 4) & 1, u >> 5, As, Bs);
        return;
    }
    // pair attention
    __shared__ float wsum[4];
    int p = id - 256;
    long bh = (long)pair_h[p] * NHEADS * (S_LEN / 8);
    long bt = (long)pair_t[p] * NHEADS * (S_LEN / 8);
    int s8 = threadIdx.x;
    float a0 = 0, a1 = 0, a2 = 0, a3 = 0, a4 = 0, a5 = 0, a6 = 0, a7 = 0;
#pragma unroll
    for (int h = 0; h < NHEADS; ++h) {
        uint4 xa = ea[bh + h * (S_LEN / 8) + s8];
        uint4 xb = ea[bt + h * (S_LEN / 8) + s8];
        a0 += bflo(xa.x) * bflo(xb.x); a1 += bfhi(xa.x) * bfhi(xb.x);
        a2 += bflo(xa.y) * bflo(xb.y); a3 += bfhi(xa.y) * bfhi(xb.y);
        a4 += bflo(xa.z) * bflo(xb.z); a5 += bfhi(xa.z) * bfhi(xb.z);
        a6 += bflo(xa.w) * bflo(xb.w); a7 += bfhi(xa.w) * bfhi(xb.w);
    }
    float psum = a0 + a1 + a2 + a3 + a4 + a5 + a6 + a7;
#pragma unroll
    for (int off = 32; off > 0; off >>= 1)
        psum += __shfl_down(psum, off, 64);
    int lane = threadIdx.x & 63, wid = threadIdx.x >> 6;
    if (lane == 0) wsum[wid] = psum;
    __syncthreads();
    float inv = 1.f / (wsum[0] + wsum[1] + wsum[2] + wsum[3] + 1e-6f);
    uint4 o;
    o.x = pk2(a0 * inv, a1 * inv); o.y = pk2(a2 * inv, a3 * inv);
    o.z = pk2(a4 * inv, a5 * inv); o.w = pk2(a6 * inv, a7 * inv);
    patt[(long)p * (S_LEN / 8) + s8] = o;
}

// ---------------------------------------------------------------------------
// L3) flat grid 768: [0,512) ctxp GEMM (bf16 partials, splitK=4, XCD-chunked);
//                    [512,768) ehet 4-slice reduce -> fp32
// ---------------------------------------------------------------------------
__launch_bounds__(256)
__global__ void gemm_ctxp_reduce(const __hip_bfloat16* __restrict__ pattB,
                                 const __hip_bfloat16* __restrict__ seqWT,
                                 __hip_bfloat16* __restrict__ ctxpB,
                                 const float* __restrict__ ehetP,
                                 float* __restrict__ ehet)
{
    __shared__ short As[8][128][8];
    __shared__ short Bs[8][128][8];
    int id = blockIdx.x;
    if (id < 512) {
        // XCD-chunked bijection: all 64 blocks of an XCD share bx (same B tile)
        int f = (id & 7) * 64 + (id >> 3);
        int bx = f >> 6, inner = f & 63;
        int by = inner & 15, bz = inner >> 4;
        gemm_core<3>(pattB, seqWT, ctxpB, nullptr, nullptr,
                     NP, PHID, S_LEN, S_LEN / 4, bx, by, bz, As, Bs);
        return;
    }
    // ehet reduce: 256 blocks x 256 threads x 8 floats = 512K elems
    long i = (long)(id - 512) * 2048 + (long)threadIdx.x * 8;
    const long n = (long)NE * 2 * PHID;
    float4 s0 = make_float4(0.f, 0.f, 0.f, 0.f), s1 = s0;
#pragma unroll
    for (int s = 0; s < 4; ++s) {
        float4 a = *(const float4*)&ehetP[s * n + i];
        float4 b = *(const float4*)&ehetP[s * n + i + 4];
        s0.x += a.x; s0.y += a.y; s0.z += a.z; s0.w += a.w;
        s1.x += b.x; s1.y += b.y; s1.z += b.z; s1.w += b.w;
    }
    *(float4*)&ehet[i] = s0;
    *(float4*)&ehet[i + 4] = s1;
}

// ---------------------------------------------------------------------------
// L4) zs/zo (+ out = b_bil init): folds ctxp 4-slice bf16 sum; 4 j per thread
// ---------------------------------------------------------------------------
__global__ void zs_zo_kernel(const __hip_bfloat16* __restrict__ ctxpB,  // [4][P][PH] bf16
                             const float* __restrict__ ehet,            // [E][2PH]
                             const float* __restrict__ b_head,
                             const float* __restrict__ b_tail,
                             const int* __restrict__ pair_h,
                             const int* __restrict__ pair_t,
                             __hip_bfloat16* __restrict__ zs,
                             __hip_bfloat16* __restrict__ zo,
                             const float* __restrict__ b_bil, float* __restrict__ out)
{
    long base = ((long)blockIdx.x * 256 + threadIdx.x) * 4;
    if (base < NP) {
        float bb = b_bil[0];
#pragma unroll
        for (int i = 0; i < 4; ++i) out[base + i] = bb;
    }
    int p = (int)(base >> 10);
    int j = (int)(base & (PHID - 1));
    const long n = (long)NP * PHID;
    float c0 = 0.f, c1 = 0.f, c2 = 0.f, c3 = 0.f;
#pragma unroll
    for (int s = 0; s < 4; ++s) {
        uint2 u = *(const uint2*)&ctxpB[s * n + base];
        c0 += bflo(u.x); c1 += bfhi(u.x); c2 += bflo(u.y); c3 += bfhi(u.y);
    }
    float4 eh = *(const float4*)&ehet[(long)pair_h[p] * 2048 + j];
    float4 et = *(const float4*)&ehet[(long)pair_t[p] * 2048 + 1024 + j];
    float4 bh = *(const float4*)&b_head[j];
    float4 bt = *(const float4*)&b_tail[j];
    float h0 = tanhf(eh.x + bh.x + c0), h1 = tanhf(eh.y + bh.y + c1);
    float h2 = tanhf(eh.z + bh.z + c2), h3 = tanhf(eh.w + bh.w + c3);
    float t0 = tanhf(et.x + bt.x + c0), t1 = tanhf(et.y + bt.y + c1);
    float t2 = tanhf(et.z + bt.z + c2), t3 = tanhf(et.w + bt.w + c3);
    uint2 ozs; ozs.x = pk2(h0, h1); ozs.y = pk2(h2, h3);
    uint2 ozo; ozo.x = pk2(t0, t1); ozo.y = pk2(t2, t3);
    *(uint2*)&zs[base] = ozs;
    *(uint2*)&zo[base] = ozo;
}

// ---------------------------------------------------------------------------
// L5) fused bilinear: A=zo, Bt=W_bil (row-major cast), dot vs zs
// ---------------------------------------------------------------------------
template <int MODE>
__launch_bounds__(256)
__global__ void gemm_single(const __hip_bfloat16* __restrict__ A,
                            const __hip_bfloat16* __restrict__ Bt,
                            void* __restrict__ Cout,
                            const __hip_bfloat16* __restrict__ zvec,
                            float* __restrict__ out,
                            int M, int N, int Kstride, int kLen)
{
    __shared__ short As[8][128][8];
    __shared__ short Bs[8][128][8];
    gemm_core<MODE>(A, Bt, Cout, zvec, out, M, N, Kstride, kLen,
                    blockIdx.x, blockIdx.y, blockIdx.z, As, Bs);
}

// ---------------------------------------------------------------------------
// Launch
// ---------------------------------------------------------------------------
extern "C" void kernel_launch(void* const* d_in, const int* in_sizes, int n_in,
                              void* d_out, int out_size, void* d_ws, size_t ws_size,
                              hipStream_t stream)
{
    const float* seq        = (const float*)d_in[0];
    const float* attention  = (const float*)d_in[1];
    const int*   mention_idx= (const int*)  d_in[2];
    const int*   entity_ids = (const int*)  d_in[3];
    const int*   pair_h     = (const int*)  d_in[4];
    const int*   pair_t     = (const int*)  d_in[5];
    const float* W_head     = (const float*)d_in[6];
    const float* b_head     = (const float*)d_in[7];
    const float* W_tail     = (const float*)d_in[8];
    const float* b_tail     = (const float*)d_in[9];
    const float* W_ctx      = (const float*)d_in[10];
    const float* W_bil      = (const float*)d_in[11];
    const float* b_bil      = (const float*)d_in[12];
    float* out = (float*)d_out;

    // ---- workspace (MB offsets) ----
    char* w = (char*)d_ws;
    __hip_bfloat16* seqB  = (__hip_bfloat16*)(w + 0);           // [S][H]       4 MB
    __hip_bfloat16* WctxT = (__hip_bfloat16*)(w + (4l << 20));  // [PH][H]      2 MB
    __hip_bfloat16* WhtT  = (__hip_bfloat16*)(w + (6l << 20));  // [2PH][H]     4 MB
    __hip_bfloat16* WbilB = (__hip_bfloat16*)(w + (10l << 20)); // [PH][PH]     2 MB (row-major cast)
    __hip_bfloat16* embB  = (__hip_bfloat16*)(w + (12l << 20)); // [E][H]       0.5 MB
    __hip_bfloat16* eaB   = (__hip_bfloat16*)(w + (13l << 20)); // [E][16][S]   16 MB
    __hip_bfloat16* pattB = (__hip_bfloat16*)(w + (29l << 20)); // [P][S]       8 MB
    __hip_bfloat16* seqWT = (__hip_bfloat16*)(w + (37l << 20)); // [PH][S]      4 MB
    __hip_bfloat16* zsB   = (__hip_bfloat16*)(w + (41l << 20)); // [P][PH]      4 MB
    __hip_bfloat16* zoB   = (__hip_bfloat16*)(w + (45l << 20)); // [P][PH]      4 MB
    __hip_bfloat16* ctxpB = (__hip_bfloat16*)(w + (49l << 20)); // [4][P][PH]   16 MB
    float* ehetP = (float*)(w + (65l << 20));                   // [4][E][2PH]  8 MB
    float* ehet  = (float*)(w + (73l << 20));                   // [E][2PH]     2 MB

    // ---- L1: prep (casts + transposes) + entity emb/att ----
    prep_ent_kernel<<<8960, 256, 0, stream>>>(seq, attention, W_ctx, W_head, W_tail, W_bil,
                                              mention_idx, entity_ids,
                                              seqB, WctxT, WhtT, WhtT + (long)PHID * HID, WbilB,
                                              (uint2*)eaB, embB);

    // ---- L2: seqW GEMM + ehet GEMM + pair attention ----
    pair_seqw_ehet<<<2304, 256, 0, stream>>>(WctxT, seqB, seqWT, embB, WhtT, ehetP,
                                             (const uint4*)eaB, pair_h, pair_t, (uint4*)pattB);

    // ---- L3: ctxp bf16 partials (splitK=4) + ehet reduce ----
    gemm_ctxp_reduce<<<768, 256, 0, stream>>>(pattB, seqWT, ctxpB, ehetP, ehet);

    // ---- L4: zs/zo (bf16) + out=b_bil ----
    zs_zo_kernel<<<2048, 256, 0, stream>>>(ctxpB, ehet, b_head, b_tail, pair_h, pair_t,
                                           zsB, zoB, b_bil, out);

    // ---- L5: fused bilinear: out[p] += zs.(W_bil @ zo) via A=zo, Bt=W_bil, dot zs ----
    gemm_single<2><<<dim3(8, 16, 2), 256, 0, stream>>>(zoB, WbilB, nullptr, zsB, out,
                                                       NP, PHID, HID, HID / 2);
}

// Round 9
// 136.647 us; speedup vs baseline: 1.5471x; 1.0233x over previous
//
#include <hip/hip_runtime.h>
#include <hip/hip_bf16.h>
#include <math.h>
#include <stdint.h>

// Problem constants
#define S_LEN  2048
#define HID    1024
#define NHEADS 16
#define NE     256
#define NMEN   1024
#define NP     2048
#define PHID   1024

typedef __attribute__((ext_vector_type(8))) short bf16x8;
typedef __attribute__((ext_vector_type(4))) float f32x4;
typedef unsigned int uint;

// ---------------------------------------------------------------------------
// Helpers
// ---------------------------------------------------------------------------
__device__ inline void seg_bounds(const int* __restrict__ entity_ids, int e,
                                  int& start, int& end) {
    int lo = 0, hi = NMEN;
    while (lo < hi) { int mid = (lo + hi) >> 1; if (entity_ids[mid] < e) lo = mid + 1; else hi = mid; }
    start = lo;
    hi = NMEN;
    while (lo < hi) { int mid = (lo + hi) >> 1; if (entity_ids[mid] <= e) lo = mid + 1; else hi = mid; }
    end = lo;
}

__device__ __forceinline__ void load_lds16(const void* g, void* l) {
    __builtin_amdgcn_global_load_lds(
        (const __attribute__((address_space(1))) uint32_t*)g,
        (__attribute__((address_space(3))) uint32_t*)l,
        16, 0, 0);
}

__device__ __forceinline__ float bflo(uint u) { return __uint_as_float(u << 16); }
__device__ __forceinline__ float bfhi(uint u) { return __uint_as_float(u & 0xffff0000u); }
__device__ __forceinline__ uint pk2(float a, float b) {
    __hip_bfloat16 ha = __float2bfloat16(a), hb = __float2bfloat16(b);
    unsigned short ua = *(unsigned short*)&ha, ub = *(unsigned short*)&hb;
    return (uint)ua | ((uint)ub << 16);
}

// ---------------------------------------------------------------------------
// L1) Merged prep + entity kernel, flat grid 8960 blocks:
//   [0,1024)      seq fp32 -> bf16 cast (row-major)
//   [1024,4096)   3 weight transposes (W_ctx, W_head, W_tail) -> bf16
//   [4096,4608)   W_bil fp32 -> bf16 cast (row-major)
//   [4608,8960)   entity: e = t&255, role = t>>8 (0..15: att head; 16: emb)
// ---------------------------------------------------------------------------
__global__ void prep_ent_kernel(const float* __restrict__ seq,
                                const float* __restrict__ attention,
                                const float* __restrict__ w0, const float* __restrict__ w1,
                                const float* __restrict__ w2, const float* __restrict__ wbil,
                                const int* __restrict__ mention_idx,
                                const int* __restrict__ entity_ids,
                                __hip_bfloat16* __restrict__ seqB,
                                __hip_bfloat16* __restrict__ o0, __hip_bfloat16* __restrict__ o1,
                                __hip_bfloat16* __restrict__ o2, __hip_bfloat16* __restrict__ obil,
                                uint2* __restrict__ eaB,
                                __hip_bfloat16* __restrict__ ent_emb)
{
    __shared__ float tbuf[32][33];
    __shared__ int sb[2];
    int id = blockIdx.x;
    if (id < 1024) {
        long i = (long)id * 256 + threadIdx.x;
        const float4* in4 = (const float4*)seq;
        float4 a = in4[2 * i], b = in4[2 * i + 1];
        uint4 o;
        o.x = pk2(a.x, a.y); o.y = pk2(a.z, a.w);
        o.z = pk2(b.x, b.y); o.w = pk2(b.z, b.w);
        ((uint4*)seqB)[i] = o;
        return;
    }
    if (id < 4096) {
        int t = id - 1024;
        int z = t >> 10;
        const float* in = (z == 0) ? w0 : (z == 1) ? w1 : w2;
        __hip_bfloat16* out = (z == 0) ? o0 : (z == 1) ? o1 : o2;
        int r0 = ((t >> 5) & 31) * 32, c0 = (t & 31) * 32;
        int j = threadIdx.x & 31, i0 = threadIdx.x >> 5;
        for (int i = i0; i < 32; i += 8)
            tbuf[i][j] = in[(long)(r0 + i) * 1024 + c0 + j];
        __syncthreads();
        for (int i = i0; i < 32; i += 8)
            out[(long)(c0 + i) * 1024 + r0 + j] = __float2bfloat16(tbuf[j][i]);
        return;
    }
    if (id < 4608) {
        long i = (long)(id - 4096) * 256 + threadIdx.x;
        const float4* in4 = (const float4*)wbil;
        float4 a = in4[2 * i], b = in4[2 * i + 1];
        uint4 o;
        o.x = pk2(a.x, a.y); o.y = pk2(a.z, a.w);
        o.z = pk2(b.x, b.y); o.w = pk2(b.z, b.w);
        ((uint4*)obil)[i] = o;
        return;
    }
    // entity work
    int t = id - 4608;
    int e = t & 255, role = t >> 8;
    if (threadIdx.x == 0) { int s, tt; seg_bounds(entity_ids, e, s, tt); sb[0] = s; sb[1] = tt; }
    __syncthreads();
    int start = sb[0], end = sb[1];

    if (role < 16) {
        const float4* att4 = (const float4*)attention;
        int h = role;
        float inv = 1.f / fmaxf((float)(end - start), 1.f);
        for (int s4 = threadIdx.x; s4 < S_LEN / 4; s4 += 256) {
            float ax = 0.f, ay = 0.f, az = 0.f, aw = 0.f;
            for (int i = start; i < end; ++i) {
                float4 v = att4[((long)h * S_LEN + mention_idx[i]) * (S_LEN / 4) + s4];
                ax += v.x; ay += v.y; az += v.z; aw += v.w;
            }
            uint2 o; o.x = pk2(ax * inv, ay * inv); o.y = pk2(az * inv, aw * inv);
            eaB[((long)e * NHEADS + h) * (S_LEN / 4) + s4] = o;
        }
    } else {
        const float4* seq4 = (const float4*)seq;
        int col4 = threadIdx.x;
        uint2 o;
        if (end <= start) {
            o.x = 0; o.y = 0;
            ((uint2*)ent_emb)[(long)e * 256 + col4] = o;
            return;
        }
        float mx = -INFINITY, my = -INFINITY, mz = -INFINITY, mw = -INFINITY;
        for (int i = start; i < end; ++i) {
            float4 v = seq4[(long)mention_idx[i] * 256 + col4];
            mx = fmaxf(mx, v.x); my = fmaxf(my, v.y); mz = fmaxf(mz, v.z); mw = fmaxf(mw, v.w);
        }
        float sx = 0.f, sy = 0.f, sz = 0.f, sw = 0.f;
        for (int i = start; i < end; ++i) {
            float4 v = seq4[(long)mention_idx[i] * 256 + col4];
            sx += expf(v.x - mx); sy += expf(v.y - my); sz += expf(v.z - mz); sw += expf(v.w - mw);
        }
        o.x = pk2(mx + logf(sx), my + logf(sy));
        o.y = pk2(mz + logf(sz), mw + logf(sw));
        ((uint2*)ent_emb)[(long)e * 256 + col4] = o;
    }
}

// ---------------------------------------------------------------------------
// Shared GEMM epilogue (all cores): 128x128 tile, 4 waves (2x2).
//    MODE 0: fp32 partial at slice bz
//    MODE 1: bf16 direct (no split)
//    MODE 2: fused bilinear: atomicAdd(out+row, sum_col acc*bf16(zvec)[row][col])
//    MODE 3: bf16 partial at slice bz
// ---------------------------------------------------------------------------
template <int MODE>
__device__ __forceinline__ void gemm_epilogue(
    f32x4 (&acc)[4][4], void* __restrict__ Cout,
    const __hip_bfloat16* __restrict__ zvec, float* __restrict__ out,
    int M, int N, int bm, int bn, int bz, int wr, int wc, int lane)
{
    int lr = lane & 15;
    int q4 = (lane >> 4) * 4;
    if (MODE == 0) {
#pragma unroll
        for (int fm = 0; fm < 4; ++fm)
#pragma unroll
            for (int fn = 0; fn < 4; ++fn) {
                int row = bm + wr * 64 + fm * 16 + q4;
                int col = bn + wc * 64 + fn * 16 + lr;
#pragma unroll
                for (int r = 0; r < 4; ++r)
                    ((float*)Cout)[((long)bz * M + row + r) * N + col] = acc[fm][fn][r];
            }
    } else if (MODE == 1) {
#pragma unroll
        for (int fm = 0; fm < 4; ++fm)
#pragma unroll
            for (int fn = 0; fn < 4; ++fn) {
                int row = bm + wr * 64 + fm * 16 + q4;
                int col = bn + wc * 64 + fn * 16 + lr;
#pragma unroll
                for (int r = 0; r < 4; ++r)
                    ((__hip_bfloat16*)Cout)[(long)(row + r) * N + col] = __float2bfloat16(acc[fm][fn][r]);
            }
    } else if (MODE == 3) {
#pragma unroll
        for (int fm = 0; fm < 4; ++fm)
#pragma unroll
            for (int fn = 0; fn < 4; ++fn) {
                int row = bm + wr * 64 + fm * 16 + q4;
                int col = bn + wc * 64 + fn * 16 + lr;
#pragma unroll
                for (int r = 0; r < 4; ++r)
                    ((__hip_bfloat16*)Cout)[((long)bz * M + row + r) * N + col] = __float2bfloat16(acc[fm][fn][r]);
            }
    } else {
#pragma unroll
        for (int fm = 0; fm < 4; ++fm) {
#pragma unroll
            for (int r = 0; r < 4; ++r) {
                int row = bm + wr * 64 + fm * 16 + q4 + r;
                float v = 0.f;
#pragma unroll
                for (int fn = 0; fn < 4; ++fn) {
                    int col = bn + wc * 64 + fn * 16 + lr;
                    v += acc[fm][fn][r] * __bfloat162float(zvec[(long)row * N + col]);
                }
                v += __shfl_xor(v, 1, 64);
                v += __shfl_xor(v, 2, 64);
                v += __shfl_xor(v, 4, 64);
                v += __shfl_xor(v, 8, 64);
                if (lr == 0) atomicAdd(out + row, v);
            }
        }
    }
}

// ---------------------------------------------------------------------------
// Single-buffer GEMM core (32 KB LDS) — used inside L2 (keeps pair_att occupancy)
// ---------------------------------------------------------------------------
template <int MODE>
__device__ __forceinline__ void gemm_core(
    const __hip_bfloat16* __restrict__ A,
    const __hip_bfloat16* __restrict__ Bt,
    void* __restrict__ Cout, const __hip_bfloat16* __restrict__ zvec, float* __restrict__ out,
    int M, int N, int Kstride, int kLen,
    int bx, int by, int bz,
    short (*As)[128][8], short (*Bs)[128][8])
{
    int tid = threadIdx.x;
    int lane = tid & 63, wid = tid >> 6;
    int wr = wid >> 1, wc = wid & 1;
    int bm = by * 128, bn = bx * 128;
    int kBeg = bz * kLen;

    const __hip_bfloat16* gsrc[8];
    void* ldst[8];
#pragma unroll
    for (int i = 0; i < 8; ++i) {
        int c = wid * 8 + i;
        int isA = (c < 16) ? 1 : 0;
        int cc = isA ? c : c - 16;
        int kg2 = cc >> 1, rh = cc & 1;
        gsrc[i] = (isA ? A + (long)(bm + rh * 64 + lane) * Kstride
                       : Bt + (long)(bn + rh * 64 + lane) * Kstride) + kBeg + kg2 * 8;
        ldst[i] = isA ? (void*)&As[kg2][rh * 64][0] : (void*)&Bs[kg2][rh * 64][0];
    }

    f32x4 acc[4][4] = {};
    int kg = lane >> 4, lr = lane & 15;

    for (int k0 = 0; k0 < kLen; k0 += 64) {
#pragma unroll
        for (int i = 0; i < 8; ++i)
            load_lds16(gsrc[i] + k0, ldst[i]);
        __syncthreads();
#pragma unroll
        for (int sub = 0; sub < 2; ++sub) {
            bf16x8 af[4], bfr[4];
#pragma unroll
            for (int f = 0; f < 4; ++f) {
                af[f]  = *(const bf16x8*)&As[sub * 4 + kg][wr * 64 + f * 16 + lr][0];
                bfr[f] = *(const bf16x8*)&Bs[sub * 4 + kg][wc * 64 + f * 16 + lr][0];
            }
#pragma unroll
            for (int fm = 0; fm < 4; ++fm)
#pragma unroll
                for (int fn = 0; fn < 4; ++fn)
                    acc[fm][fn] = __builtin_amdgcn_mfma_f32_16x16x32_bf16(af[fm], bfr[fn], acc[fm][fn], 0, 0, 0);
        }
        __syncthreads();
    }
    gemm_epilogue<MODE>(acc, Cout, zvec, out, M, N, bm, bn, bz, wr, wc, lane);
}

// ---------------------------------------------------------------------------
// Double-buffered prefetch GEMM core (64 KB LDS, T3 2-phase).
// Requires kLen % 128 == 0 (even number of BK=64 steps).
// Per step: issue next-tile global_load_lds into the OTHER buffer, then
// ds_read+MFMA current buffer, then one barrier (drains vmcnt) per step.
// ---------------------------------------------------------------------------
template <int MODE>
__device__ __forceinline__ void gemm_core_db(
    const __hip_bfloat16* __restrict__ A,
    const __hip_bfloat16* __restrict__ Bt,
    void* __restrict__ Cout, const __hip_bfloat16* __restrict__ zvec, float* __restrict__ out,
    int M, int N, int Kstride, int kLen,
    int bx, int by, int bz,
    short (*As)[8][128][8], short (*Bs)[8][128][8])   // [2] buffers
{
    int tid = threadIdx.x;
    int lane = tid & 63, wid = tid >> 6;
    int wr = wid >> 1, wc = wid & 1;
    int bm = by * 128, bn = bx * 128;
    int kBeg = bz * kLen;

    const __hip_bfloat16* gsrc[8];
    void *ld0[8], *ld1[8];
#pragma unroll
    for (int i = 0; i < 8; ++i) {
        int c = wid * 8 + i;
        int isA = (c < 16) ? 1 : 0;
        int cc = isA ? c : c - 16;
        int kg2 = cc >> 1, rh = cc & 1;
        gsrc[i] = (isA ? A + (long)(bm + rh * 64 + lane) * Kstride
                       : Bt + (long)(bn + rh * 64 + lane) * Kstride) + kBeg + kg2 * 8;
        ld0[i] = isA ? (void*)&As[0][kg2][rh * 64][0] : (void*)&Bs[0][kg2][rh * 64][0];
        ld1[i] = isA ? (void*)&As[1][kg2][rh * 64][0] : (void*)&Bs[1][kg2][rh * 64][0];
    }

    f32x4 acc[4][4] = {};
    int kg = lane >> 4, lr = lane & 15;
    int nSteps = kLen >> 6;   // even by contract

#define STAGE_DB(t, ld) { _Pragma("unroll") \
    for (int i = 0; i < 8; ++i) load_lds16(gsrc[i] + (t) * 64, ld[i]); }
#define COMPUTE_DB(AsB, BsB) { _Pragma("unroll") \
    for (int sub = 0; sub < 2; ++sub) { \
        bf16x8 af[4], bfr[4]; \
        _Pragma("unroll") for (int f = 0; f < 4; ++f) { \
            af[f]  = *(const bf16x8*)&AsB[sub * 4 + kg][wr * 64 + f * 16 + lr][0]; \
            bfr[f] = *(const bf16x8*)&BsB[sub * 4 + kg][wc * 64 + f * 16 + lr][0]; \
        } \
        _Pragma("unroll") for (int fm = 0; fm < 4; ++fm) \
        _Pragma("unroll") for (int fn = 0; fn < 4; ++fn) \
            acc[fm][fn] = __builtin_amdgcn_mfma_f32_16x16x32_bf16(af[fm], bfr[fn], acc[fm][fn], 0, 0, 0); \
    } }

    STAGE_DB(0, ld0);
    __syncthreads();                         // buf0 ready
    for (int step = 0; step < nSteps; step += 2) {
        STAGE_DB(step + 1, ld1);             // prefetch -> buf1 (in flight during MFMA)
        COMPUTE_DB(As[0], Bs[0]);
        __syncthreads();                     // buf1 ready; buf0 reads done
        if (step + 2 < nSteps) STAGE_DB(step + 2, ld0);
        COMPUTE_DB(As[1], Bs[1]);
        __syncthreads();                     // buf0 ready; buf1 reads done
    }
#undef STAGE_DB
#undef COMPUTE_DB
    gemm_epilogue<MODE>(acc, Cout, zvec, out, M, N, bm, bn, bz, wr, wc, lane);
}

// ---------------------------------------------------------------------------
// L2) Merged: seqW GEMM (128 blocks, MODE 1) + ehet GEMM (128 blocks, splitK=4)
//     + pair attention (2048 blocks). 32 KB LDS keeps pair occupancy high.
// ---------------------------------------------------------------------------
__launch_bounds__(256)
__global__ void pair_seqw_ehet(const __hip_bfloat16* __restrict__ WctxT,
                               const __hip_bfloat16* __restrict__ seqB,
                               __hip_bfloat16* __restrict__ seqWT,
                               const __hip_bfloat16* __restrict__ embB,
                               const __hip_bfloat16* __restrict__ WhtT,
                               float* __restrict__ ehetP,
                               const uint4* __restrict__ ea,
                               const int* __restrict__ pair_h,
                               const int* __restrict__ pair_t,
                               uint4* __restrict__ patt)
{
    __shared__ short As[8][128][8];
    __shared__ short Bs[8][128][8];
    int id = blockIdx.x;
    if (id < 128) {
        gemm_core<1>(WctxT, seqB, seqWT, nullptr, nullptr,
                     PHID, S_LEN, HID, HID, id & 15, id >> 4, 0, As, Bs);
        return;
    }
    if (id < 256) {
        int u = id - 128;
        gemm_core<0>(embB, WhtT, ehetP, nullptr, nullptr,
                     NE, 2 * PHID, HID, HID / 4, u & 15, (u >> 4) & 1, u >> 5, As, Bs);
        return;
    }
    // pair attention
    __shared__ float wsum[4];
    int p = id - 256;
    long bh = (long)pair_h[p] * NHEADS * (S_LEN / 8);
    long bt = (long)pair_t[p] * NHEADS * (S_LEN / 8);
    int s8 = threadIdx.x;
    float a0 = 0, a1 = 0, a2 = 0, a3 = 0, a4 = 0, a5 = 0, a6 = 0, a7 = 0;
#pragma unroll
    for (int h = 0; h < NHEADS; ++h) {
        uint4 xa = ea[bh + h * (S_LEN / 8) + s8];
        uint4 xb = ea[bt + h * (S_LEN / 8) + s8];
        a0 += bflo(xa.x) * bflo(xb.x); a1 += bfhi(xa.x) * bfhi(xb.x);
        a2 += bflo(xa.y) * bflo(xb.y); a3 += bfhi(xa.y) * bfhi(xb.y);
        a4 += bflo(xa.z) * bflo(xb.z); a5 += bfhi(xa.z) * bfhi(xb.z);
        a6 += bflo(xa.w) * bflo(xb.w); a7 += bfhi(xa.w) * bfhi(xb.w);
    }
    float psum = a0 + a1 + a2 + a3 + a4 + a5 + a6 + a7;
#pragma unroll
    for (int off = 32; off > 0; off >>= 1)
        psum += __shfl_down(psum, off, 64);
    int lane = threadIdx.x & 63, wid = threadIdx.x >> 6;
    if (lane == 0) wsum[wid] = psum;
    __syncthreads();
    float inv = 1.f / (wsum[0] + wsum[1] + wsum[2] + wsum[3] + 1e-6f);
    uint4 o;
    o.x = pk2(a0 * inv, a1 * inv); o.y = pk2(a2 * inv, a3 * inv);
    o.z = pk2(a4 * inv, a5 * inv); o.w = pk2(a6 * inv, a7 * inv);
    patt[(long)p * (S_LEN / 8) + s8] = o;
}

// ---------------------------------------------------------------------------
// L3) flat grid 768: [0,512) ctxp GEMM (bf16 partials, splitK=4, XCD-chunked,
//                    double-buffered); [512,768) ehet 4-slice reduce -> fp32
// ---------------------------------------------------------------------------
__launch_bounds__(256)
__global__ void gemm_ctxp_reduce(const __hip_bfloat16* __restrict__ pattB,
                                 const __hip_bfloat16* __restrict__ seqWT,
                                 __hip_bfloat16* __restrict__ ctxpB,
                                 const float* __restrict__ ehetP,
                                 float* __restrict__ ehet)
{
    __shared__ short As[2][8][128][8];
    __shared__ short Bs[2][8][128][8];
    int id = blockIdx.x;
    if (id < 512) {
        // XCD-chunked bijection: all 64 blocks of an XCD share bx (same B tile)
        int f = (id & 7) * 64 + (id >> 3);
        int bx = f >> 6, inner = f & 63;
        int by = inner & 15, bz = inner >> 4;
        gemm_core_db<3>(pattB, seqWT, ctxpB, nullptr, nullptr,
                        NP, PHID, S_LEN, S_LEN / 4, bx, by, bz, As, Bs);
        return;
    }
    // ehet reduce: 256 blocks x 256 threads x 8 floats = 512K elems
    long i = (long)(id - 512) * 2048 + (long)threadIdx.x * 8;
    const long n = (long)NE * 2 * PHID;
    float4 s0 = make_float4(0.f, 0.f, 0.f, 0.f), s1 = s0;
#pragma unroll
    for (int s = 0; s < 4; ++s) {
        float4 a = *(const float4*)&ehetP[s * n + i];
        float4 b = *(const float4*)&ehetP[s * n + i + 4];
        s0.x += a.x; s0.y += a.y; s0.z += a.z; s0.w += a.w;
        s1.x += b.x; s1.y += b.y; s1.z += b.z; s1.w += b.w;
    }
    *(float4*)&ehet[i] = s0;
    *(float4*)&ehet[i + 4] = s1;
}

// ---------------------------------------------------------------------------
// L4) zs/zo (+ out = b_bil init): folds ctxp 4-slice bf16 sum; 4 j per thread
// ---------------------------------------------------------------------------
__global__ void zs_zo_kernel(const __hip_bfloat16* __restrict__ ctxpB,  // [4][P][PH] bf16
                             const float* __restrict__ ehet,            // [E][2PH]
                             const float* __restrict__ b_head,
                             const float* __restrict__ b_tail,
                             const int* __restrict__ pair_h,
                             const int* __restrict__ pair_t,
                             __hip_bfloat16* __restrict__ zs,
                             __hip_bfloat16* __restrict__ zo,
                             const float* __restrict__ b_bil, float* __restrict__ out)
{
    long base = ((long)blockIdx.x * 256 + threadIdx.x) * 4;
    if (base < NP) {
        float bb = b_bil[0];
#pragma unroll
        for (int i = 0; i < 4; ++i) out[base + i] = bb;
    }
    int p = (int)(base >> 10);
    int j = (int)(base & (PHID - 1));
    const long n = (long)NP * PHID;
    float c0 = 0.f, c1 = 0.f, c2 = 0.f, c3 = 0.f;
#pragma unroll
    for (int s = 0; s < 4; ++s) {
        uint2 u = *(const uint2*)&ctxpB[s * n + base];
        c0 += bflo(u.x); c1 += bfhi(u.x); c2 += bflo(u.y); c3 += bfhi(u.y);
    }
    float4 eh = *(const float4*)&ehet[(long)pair_h[p] * 2048 + j];
    float4 et = *(const float4*)&ehet[(long)pair_t[p] * 2048 + 1024 + j];
    float4 bh = *(const float4*)&b_head[j];
    float4 bt = *(const float4*)&b_tail[j];
    float h0 = tanhf(eh.x + bh.x + c0), h1 = tanhf(eh.y + bh.y + c1);
    float h2 = tanhf(eh.z + bh.z + c2), h3 = tanhf(eh.w + bh.w + c3);
    float t0 = tanhf(et.x + bt.x + c0), t1 = tanhf(et.y + bt.y + c1);
    float t2 = tanhf(et.z + bt.z + c2), t3 = tanhf(et.w + bt.w + c3);
    uint2 ozs; ozs.x = pk2(h0, h1); ozs.y = pk2(h2, h3);
    uint2 ozo; ozo.x = pk2(t0, t1); ozo.y = pk2(t2, t3);
    *(uint2*)&zs[base] = ozs;
    *(uint2*)&zo[base] = ozo;
}

// ---------------------------------------------------------------------------
// L5) fused bilinear (double-buffered): A=zo, Bt=W_bil row-major, dot vs zs
// ---------------------------------------------------------------------------
template <int MODE>
__launch_bounds__(256)
__global__ void gemm_single_db(const __hip_bfloat16* __restrict__ A,
                               const __hip_bfloat16* __restrict__ Bt,
                               void* __restrict__ Cout,
                               const __hip_bfloat16* __restrict__ zvec,
                               float* __restrict__ out,
                               int M, int N, int Kstride, int kLen)
{
    __shared__ short As[2][8][128][8];
    __shared__ short Bs[2][8][128][8];
    gemm_core_db<MODE>(A, Bt, Cout, zvec, out, M, N, Kstride, kLen,
                       blockIdx.x, blockIdx.y, blockIdx.z, As, Bs);
}

// ---------------------------------------------------------------------------
// Launch
// ---------------------------------------------------------------------------
extern "C" void kernel_launch(void* const* d_in, const int* in_sizes, int n_in,
                              void* d_out, int out_size, void* d_ws, size_t ws_size,
                              hipStream_t stream)
{
    const float* seq        = (const float*)d_in[0];
    const float* attention  = (const float*)d_in[1];
    const int*   mention_idx= (const int*)  d_in[2];
    const int*   entity_ids = (const int*)  d_in[3];
    const int*   pair_h     = (const int*)  d_in[4];
    const int*   pair_t     = (const int*)  d_in[5];
    const float* W_head     = (const float*)d_in[6];
    const float* b_head     = (const float*)d_in[7];
    const float* W_tail     = (const float*)d_in[8];
    const float* b_tail     = (const float*)d_in[9];
    const float* W_ctx      = (const float*)d_in[10];
    const float* W_bil      = (const float*)d_in[11];
    const float* b_bil      = (const float*)d_in[12];
    float* out = (float*)d_out;

    // ---- workspace (MB offsets) ----
    char* w = (char*)d_ws;
    __hip_bfloat16* seqB  = (__hip_bfloat16*)(w + 0);           // [S][H]       4 MB
    __hip_bfloat16* WctxT = (__hip_bfloat16*)(w + (4l << 20));  // [PH][H]      2 MB
    __hip_bfloat16* WhtT  = (__hip_bfloat16*)(w + (6l << 20));  // [2PH][H]     4 MB
    __hip_bfloat16* WbilB = (__hip_bfloat16*)(w + (10l << 20)); // [PH][PH]     2 MB (row-major cast)
    __hip_bfloat16* embB  = (__hip_bfloat16*)(w + (12l << 20)); // [E][H]       0.5 MB
    __hip_bfloat16* eaB   = (__hip_bfloat16*)(w + (13l << 20)); // [E][16][S]   16 MB
    __hip_bfloat16* pattB = (__hip_bfloat16*)(w + (29l << 20)); // [P][S]       8 MB
    __hip_bfloat16* seqWT = (__hip_bfloat16*)(w + (37l << 20)); // [PH][S]      4 MB
    __hip_bfloat16* zsB   = (__hip_bfloat16*)(w + (41l << 20)); // [P][PH]      4 MB
    __hip_bfloat16* zoB   = (__hip_bfloat16*)(w + (45l << 20)); // [P][PH]      4 MB
    __hip_bfloat16* ctxpB = (__hip_bfloat16*)(w + (49l << 20)); // [4][P][PH]   16 MB
    float* ehetP = (float*)(w + (65l << 20));                   // [4][E][2PH]  8 MB
    float* ehet  = (float*)(w + (73l << 20));                   // [E][2PH]     2 MB

    // ---- L1: prep (casts + transposes) + entity emb/att ----
    prep_ent_kernel<<<8960, 256, 0, stream>>>(seq, attention, W_ctx, W_head, W_tail, W_bil,
                                              mention_idx, entity_ids,
                                              seqB, WctxT, WhtT, WhtT + (long)PHID * HID, WbilB,
                                              (uint2*)eaB, embB);

    // ---- L2: seqW GEMM + ehet GEMM + pair attention ----
    pair_seqw_ehet<<<2304, 256, 0, stream>>>(WctxT, seqB, seqWT, embB, WhtT, ehetP,
                                             (const uint4*)eaB, pair_h, pair_t, (uint4*)pattB);

    // ---- L3: ctxp bf16 partials (splitK=4, dbuf) + ehet reduce ----
    gemm_ctxp_reduce<<<768, 256, 0, stream>>>(pattB, seqWT, ctxpB, ehetP, ehet);

    // ---- L4: zs/zo (bf16) + out=b_bil ----
    zs_zo_kernel<<<2048, 256, 0, stream>>>(ctxpB, ehet, b_head, b_tail, pair_h, pair_t,
                                           zsB, zoB, b_bil, out);

    // ---- L5: fused bilinear (dbuf, splitK=4) ----
    gemm_single_db<2><<<dim3(8, 16, 4), 256, 0, stream>>>(zoB, WbilB, nullptr, zsB, out,
                                                          NP, PHID, HID, HID / 4);
}